// Round 3
// baseline (3681.784 us; speedup 1.0000x reference)
//
#include <hip/hip_runtime.h>

#define ALPHA 0.005f
#define SCALE 0.001f
#define DELTA 0.1f
#define MAXIT 51   // MAX_ITER + 1 scan steps

constexpr int N = 512;
constexpr int M = 512;
constexpr int NTHREADS = 1024;
constexpr int NWAVES = NTHREADS / 64;  // 16
constexpr int MPW = M / NWAVES;        // 32 constraint rows per wave at t=0
constexpr int NROWS = 256;             // B*S
constexpr size_t WS_NEEDED = (size_t)NROWS * M * N * 2;  // bf16 A copy: 128 MiB

// Group map (group G = rows 32G..32G+31; row m = w + 16*kk, kk = 2G + h):
//   G 0..7   -> ws (global stream, 8 groups = 256 KiB/iter/CU, ws = 64 MiB)
//   G 8..11  -> register cache slots q0..q3 (32 VGPR/lane)
//   G 12..14 -> LDS cache (96 KiB, rows 384..479)
//   G 15     -> register cache slot q4
constexpr int CACHE_M0 = 384;

template<int CTRL>
__device__ __forceinline__ float dpp_mov(float v) {
    return __int_as_float(__builtin_amdgcn_update_dpp(
        0, __float_as_int(v), CTRL, 0xF, 0xF, true));
}

// 64-lane sum (t=0 fp32 phase): 6 DPP + readlane
__device__ __forceinline__ float wave_sum_u(float d) {
    d += dpp_mov<0x111>(d);   // row_shr:1
    d += dpp_mov<0x112>(d);   // row_shr:2
    d += dpp_mov<0x114>(d);   // row_shr:4
    d += dpp_mov<0x118>(d);   // row_shr:8
    d += dpp_mov<0x142>(d);   // row_bcast:15
    d += dpp_mov<0x143>(d);   // row_bcast:31
    return __int_as_float(__builtin_amdgcn_readlane(__float_as_int(d), 63));
}

__device__ __forceinline__ float dot8(const float4& a, const float4& c,
                                      const float4& xa, const float4& xb) {
    return a.x*xa.x + a.y*xa.y + a.z*xa.z + a.w*xa.w
         + c.x*xb.x + c.y*xb.y + c.z*xb.z + c.w*xb.w;
}

// bf16 pack (RNE) / unpack
__device__ __forceinline__ unsigned pack2_bf16(float f0, float f1) {
    unsigned a = __float_as_uint(f0); a += 0x7fffu + ((a >> 16) & 1u);
    unsigned b = __float_as_uint(f1); b += 0x7fffu + ((b >> 16) & 1u);
    return (a >> 16) | (b & 0xffff0000u);
}
__device__ __forceinline__ float bflo(unsigned u) { return __uint_as_float(u << 16); }
__device__ __forceinline__ float bfhi(unsigned u) { return __uint_as_float(u & 0xffff0000u); }

__device__ __forceinline__ void unpack4(uint2 u, float4& f) {
    f.x = bflo(u.x); f.y = bfhi(u.x); f.z = bflo(u.y); f.w = bfhi(u.y);
}

// ---------------------------------------------------------------------------
// One block per (b,s) row. t=0: fp32 pass; A is converted to bf16 and split
// three ways: ws (groups 0..7), register slots (8..11,15 — captured via
// pack + ds_bpermute xor32 exchange), LDS (12..14). t>=1: stream only 8
// groups from ws (L3-resident 64 MiB), rest from registers/LDS. 2 barriers
// per iteration (reduced g goes to separate gred buffer).
// ---------------------------------------------------------------------------
__global__ __launch_bounds__(NTHREADS, 4)
void lva_bf16_kernel(const float* __restrict__ x_in,
                     const float* __restrict__ A,
                     const float* __restrict__ bvec,
                     float* __restrict__ x_out,
                     unsigned short* __restrict__ wsA)
{
    __shared__ __align__(16) float b_lds[M];
    __shared__ __align__(16) float g_lds[NWAVES * N];      // 32 KiB: 16 partials
    __shared__ __align__(16) float gred[N];                // 2 KiB: reduced g
    __shared__ float sv_lds[NWAVES];
    __shared__ int bc_active;
    __shared__ __align__(16) uint2 A_lds[96 * 128];        // 96 KiB: rows 384..479

    const int tid  = threadIdx.x;
    const int lane = tid & 63;
    const int w    = tid >> 6;
    const int r    = blockIdx.x;
    const int h    = lane >> 5;          // half-wave index 0/1
    const int s    = lane & 31;          // lane-in-half
    const int xadr = (lane ^ 32) << 2;   // bpermute byte addr (xor32)

    if (tid < M) b_lds[tid] = bvec[(size_t)r * M + tid];

    const int n0 = lane * 4;
    const int n1 = 256 + lane * 4;

    const float* xrow = x_in + (size_t)r * N;
    float4 xa = *(const float4*)(xrow + n0);
    float4 xb = *(const float4*)(xrow + n1);

    const float* Ablk = A + (size_t)r * M * N + (size_t)w * N;
    unsigned short* Wblk = wsA + (size_t)r * M * N + (size_t)w * N;

    __syncthreads();

    bool alive = true;

    // register cache slots: q0..q3 = groups 8..11, q4 = group 15
    uint2 q0a = make_uint2(0,0), q0b = q0a, q0c = q0a, q0d = q0a;
    uint2 q1a = q0a, q1b = q0a, q1c = q0a, q1d = q0a;
    uint2 q2a = q0a, q2b = q0a, q2c = q0a, q2d = q0a;
    uint2 q3a = q0a, q3b = q0a, q3c = q0a, q3d = q0a;
    uint2 q4a = q0a, q4b = q0a, q4c = q0a, q4d = q0a;

    // ---- t = 0: fp32 compute; A split to ws / registers / LDS ----
    {
        float4 ga = make_float4(0.f, 0.f, 0.f, 0.f);
        float4 gb = make_float4(0.f, 0.f, 0.f, 0.f);
        float sviol = 0.f;
        float4 a0, a1, a2, a3, c0, c1, c2, c3;

        #define LOADA4(KK) do {                                               \
            const float* P0 = Ablk + (size_t)((KK) + 0) * (16 * N);           \
            const float* P1 = Ablk + (size_t)((KK) + 1) * (16 * N);           \
            const float* P2 = Ablk + (size_t)((KK) + 2) * (16 * N);           \
            const float* P3 = Ablk + (size_t)((KK) + 3) * (16 * N);           \
            a0 = *(const float4*)(P0 + n0); c0 = *(const float4*)(P0 + n1);   \
            a1 = *(const float4*)(P1 + n0); c1 = *(const float4*)(P1 + n1);   \
            a2 = *(const float4*)(P2 + n0); c2 = *(const float4*)(P2 + n1);   \
            a3 = *(const float4*)(P3 + n0); c3 = *(const float4*)(P3 + n1);   \
        } while (0)

        #define DOTGRAD4(KK) do {                                             \
            float bb0 = b_lds[w + 16 * ((KK) + 0)];                           \
            float bb1 = b_lds[w + 16 * ((KK) + 1)];                           \
            float bb2 = b_lds[w + 16 * ((KK) + 2)];                           \
            float bb3 = b_lds[w + 16 * ((KK) + 3)];                           \
            float d0 = wave_sum_u(dot8(a0, c0, xa, xb));                      \
            float d1 = wave_sum_u(dot8(a1, c1, xa, xb));                      \
            float d2 = wave_sum_u(dot8(a2, c2, xa, xb));                      \
            float d3 = wave_sum_u(dot8(a3, c3, xa, xb));                      \
            float v0 = fmaxf(d0 - bb0, 0.f);                                  \
            float v1 = fmaxf(d1 - bb1, 0.f);                                  \
            float v2 = fmaxf(d2 - bb2, 0.f);                                  \
            float v3 = fmaxf(d3 - bb3, 0.f);                                  \
            sviol += v0 + v1 + v2 + v3;                                       \
            ga.x += v0*a0.x + v1*a1.x + v2*a2.x + v3*a3.x;                    \
            ga.y += v0*a0.y + v1*a1.y + v2*a2.y + v3*a3.y;                    \
            ga.z += v0*a0.z + v1*a1.z + v2*a2.z + v3*a3.z;                    \
            ga.w += v0*a0.w + v1*a1.w + v2*a2.w + v3*a3.w;                    \
            gb.x += v0*c0.x + v1*c1.x + v2*c2.x + v3*c3.x;                    \
            gb.y += v0*c0.y + v1*c1.y + v2*c2.y + v3*c3.y;                    \
            gb.z += v0*c0.z + v1*c1.z + v2*c2.z + v3*c3.z;                    \
            gb.w += v0*c0.w + v1*c1.w + v2*c2.w + v3*c3.w;                    \
        } while (0)

        #define WS1(J, AJ, CJ) do {                                           \
            unsigned short* q = Wblk + (size_t)(J) * (16 * N);                \
            *(uint2*)(q + n0) = make_uint2(pack2_bf16(AJ.x, AJ.y),            \
                                           pack2_bf16(AJ.z, AJ.w));           \
            *(uint2*)(q + n1) = make_uint2(pack2_bf16(CJ.x, CJ.y),            \
                                           pack2_bf16(CJ.z, CJ.w));           \
        } while (0)

        #define LDS1(J, AJ, CJ) do {                                          \
            const int rl = w + 16 * (J) - CACHE_M0;                           \
            A_lds[rl * 128 + lane]      = make_uint2(pack2_bf16(AJ.x, AJ.y),  \
                                                     pack2_bf16(AJ.z, AJ.w)); \
            A_lds[rl * 128 + 64 + lane] = make_uint2(pack2_bf16(CJ.x, CJ.y),  \
                                                     pack2_bf16(CJ.z, CJ.w)); \
        } while (0)

        #define BPERM(v) (unsigned)__builtin_amdgcn_ds_bpermute(xadr, (int)(v))

        // capture row into cache slot; even kk' -> owner half h=0
        #define CAPE(Q, AJ, CJ) do {                                          \
            unsigned lo0 = pack2_bf16(AJ.x, AJ.y), lo1 = pack2_bf16(AJ.z, AJ.w); \
            unsigned hi0 = pack2_bf16(CJ.x, CJ.y), hi1 = pack2_bf16(CJ.z, CJ.w); \
            unsigned rl0 = BPERM(lo0), rl1 = BPERM(lo1);                      \
            unsigned rh0 = BPERM(hi0), rh1 = BPERM(hi1);                      \
            if (h == 0) {                                                     \
                Q##a = make_uint2(lo0, lo1); Q##b = make_uint2(rl0, rl1);     \
                Q##c = make_uint2(hi0, hi1); Q##d = make_uint2(rh0, rh1);     \
            }                                                                 \
        } while (0)
        // odd kk' -> owner half h=1 (its own lo covers cols 128+4s -> b1)
        #define CAPO(Q, AJ, CJ) do {                                          \
            unsigned lo0 = pack2_bf16(AJ.x, AJ.y), lo1 = pack2_bf16(AJ.z, AJ.w); \
            unsigned hi0 = pack2_bf16(CJ.x, CJ.y), hi1 = pack2_bf16(CJ.z, CJ.w); \
            unsigned rl0 = BPERM(lo0), rl1 = BPERM(lo1);                      \
            unsigned rh0 = BPERM(hi0), rh1 = BPERM(hi1);                      \
            if (h == 1) {                                                     \
                Q##a = make_uint2(rl0, rl1); Q##b = make_uint2(lo0, lo1);     \
                Q##c = make_uint2(rh0, rh1); Q##d = make_uint2(hi0, hi1);     \
            }                                                                 \
        } while (0)

        // Section A: kk 0..15 -> ws groups 0..7 (rolled)
        #pragma unroll 1
        for (int kk = 0; kk < 16; kk += 4) {
            LOADA4(kk);
            WS1(kk + 0, a0, c0); WS1(kk + 1, a1, c1);
            WS1(kk + 2, a2, c2); WS1(kk + 3, a3, c3);
            DOTGRAD4(kk);
        }
        // Section B: kk 16..19 -> reg slots q0 (G=8), q1 (G=9)
        LOADA4(16);
        CAPE(q0, a0, c0); CAPO(q0, a1, c1);
        CAPE(q1, a2, c2); CAPO(q1, a3, c3);
        DOTGRAD4(16);
        // Section C: kk 20..23 -> reg slots q2 (G=10), q3 (G=11)
        LOADA4(20);
        CAPE(q2, a0, c0); CAPO(q2, a1, c1);
        CAPE(q3, a2, c2); CAPO(q3, a3, c3);
        DOTGRAD4(20);
        // Section D: kk 24..27 -> A_lds (groups 12, 13-lo)
        LOADA4(24);
        LDS1(24, a0, c0); LDS1(25, a1, c1);
        LDS1(26, a2, c2); LDS1(27, a3, c3);
        DOTGRAD4(24);
        // Section E: kk 28,29 -> A_lds (group 14); kk 30,31 -> reg slot q4 (G=15)
        LOADA4(28);
        LDS1(28, a0, c0); LDS1(29, a1, c1);
        CAPE(q4, a2, c2); CAPO(q4, a3, c3);
        DOTGRAD4(28);

        #undef LOADA4
        #undef WS1
        #undef LDS1
        #undef CAPE
        #undef CAPO
        #undef BPERM
        #undef DOTGRAD4

        if (lane == 0) sv_lds[w] = sviol;
        *(float4*)(&g_lds[w * N + n0]) = ga;
        *(float4*)(&g_lds[w * N + n1]) = gb;
        __syncthreads();
        if (tid == 0) {
            float sacc = 0.f;
            #pragma unroll
            for (int i = 0; i < NWAVES; ++i) sacc += sv_lds[i];
            bc_active = (sacc >= DELTA) ? 1 : 0;
        }
        if (tid < N) {
            float sacc = 0.f;
            #pragma unroll
            for (int i = 0; i < NWAVES; ++i) sacc += g_lds[i * N + tid];
            gred[tid] = sacc;
        }
        __syncthreads();
        if (!bc_active) {
            alive = false;
        } else {
            float4 gfa = *(const float4*)(&gred[n0]);
            float4 gfb = *(const float4*)(&gred[n1]);
            xa.x = fmaxf(xa.x - (ALPHA / (1.f + SCALE*gfa.x)) * gfa.x, 0.f);
            xa.y = fmaxf(xa.y - (ALPHA / (1.f + SCALE*gfa.y)) * gfa.y, 0.f);
            xa.z = fmaxf(xa.z - (ALPHA / (1.f + SCALE*gfa.z)) * gfa.z, 0.f);
            xa.w = fmaxf(xa.w - (ALPHA / (1.f + SCALE*gfa.w)) * gfa.w, 0.f);
            xb.x = fmaxf(xb.x - (ALPHA / (1.f + SCALE*gfb.x)) * gfb.x, 0.f);
            xb.y = fmaxf(xb.y - (ALPHA / (1.f + SCALE*gfb.y)) * gfb.y, 0.f);
            xb.z = fmaxf(xb.z - (ALPHA / (1.f + SCALE*gfb.z)) * gfb.z, 0.f);
            xb.w = fmaxf(xb.w - (ALPHA / (1.f + SCALE*gfb.w)) * gfb.w, 0.f);
        }
    }

    // ---- relayout x into 32-lane-group fragments (s*4 contiguous) ----
    __syncthreads();
    if (w == 0) {
        *(float4*)(&g_lds[n0]) = xa;
        *(float4*)(&g_lds[n1]) = xb;
    }
    __syncthreads();
    float4 xf0 = *(const float4*)(&g_lds[  0 + s * 4]);
    float4 xf1 = *(const float4*)(&g_lds[128 + s * 4]);
    float4 xf2 = *(const float4*)(&g_lds[256 + s * 4]);
    float4 xf3 = *(const float4*)(&g_lds[384 + s * 4]);
    __syncthreads();

    // ---- t = 1..50: bf16 phase, half-wave per row ----
    if (alive) {
        const uint2* Wp = (const uint2*)(wsA + (size_t)r * M * N)
                          + (w + 16 * h) * 128 + s;
        const int mb = w + 16 * h;    // b_lds base; row m = mb + 32*G

        uint2 c0, c1, c2, c3, p0, p1, p2, p3;

        #define LOADG(b0, b1, b2, b3, Gn) do {  \
            b0 = Wp[(Gn) * 4096];               \
            b1 = Wp[(Gn) * 4096 + 32];          \
            b2 = Wp[(Gn) * 4096 + 64];          \
            b3 = Wp[(Gn) * 4096 + 96];          \
        } while (0)

        #define COMPUTE(b0, b1, b2, b3, G) do {                               \
            float4 f0, f1, f2, f3;                                            \
            unpack4(b0, f0); unpack4(b1, f1);                                 \
            unpack4(b2, f2); unpack4(b3, f3);                                 \
            float d = f0.x*xf0.x + f0.y*xf0.y + f0.z*xf0.z + f0.w*xf0.w       \
                    + f1.x*xf1.x + f1.y*xf1.y + f1.z*xf1.z + f1.w*xf1.w       \
                    + f2.x*xf2.x + f2.y*xf2.y + f2.z*xf2.z + f2.w*xf2.w       \
                    + f3.x*xf3.x + f3.y*xf3.y + f3.z*xf3.z + f3.w*xf3.w;      \
            d += dpp_mov<0xB1>(d);   /* quad_perm [1,0,3,2] : xor1 */         \
            d += dpp_mov<0x4E>(d);   /* quad_perm [2,3,0,1] : xor2 */         \
            d += dpp_mov<0x141>(d);  /* row_half_mirror     : xor4 */         \
            d += dpp_mov<0x140>(d);  /* row_mirror          : xor8 */         \
            d += __int_as_float(__builtin_amdgcn_ds_swizzle(                  \
                     __float_as_int(d), 0x401F)); /* xor16 within 32 */       \
            float v = fmaxf(d - b_lds[mb + 32 * (G)], 0.f);                   \
            sviol += v;                                                       \
            g0.x += v*f0.x; g0.y += v*f0.y; g0.z += v*f0.z; g0.w += v*f0.w;   \
            g1.x += v*f1.x; g1.y += v*f1.y; g1.z += v*f1.z; g1.w += v*f1.w;   \
            g2.x += v*f2.x; g2.y += v*f2.y; g2.z += v*f2.z; g2.w += v*f2.w;   \
            g3.x += v*f3.x; g3.y += v*f3.y; g3.z += v*f3.z; g3.w += v*f3.w;   \
        } while (0)

        #define MRG(x) (x) += __int_as_float(                                 \
            __builtin_amdgcn_ds_bpermute(xadr, __float_as_int(x)))

        LOADG(c0, c1, c2, c3, 0);   // prologue: G=0 in flight

        #pragma unroll 1
        for (int t = 1; t < MAXIT; ++t) {
            float4 g0 = make_float4(0.f, 0.f, 0.f, 0.f);
            float4 g1 = make_float4(0.f, 0.f, 0.f, 0.f);
            float4 g2 = make_float4(0.f, 0.f, 0.f, 0.f);
            float4 g3 = make_float4(0.f, 0.f, 0.f, 0.f);
            float sviol = 0.f;

            // 8 global groups, paired double-buffer (proven structure)
            LOADG(p0, p1, p2, p3, 1); COMPUTE(c0, c1, c2, c3, 0);
            LOADG(c0, c1, c2, c3, 2); COMPUTE(p0, p1, p2, p3, 1);
            LOADG(p0, p1, p2, p3, 3); COMPUTE(c0, c1, c2, c3, 2);
            LOADG(c0, c1, c2, c3, 4); COMPUTE(p0, p1, p2, p3, 3);
            LOADG(p0, p1, p2, p3, 5); COMPUTE(c0, c1, c2, c3, 4);
            LOADG(c0, c1, c2, c3, 6); COMPUTE(p0, p1, p2, p3, 5);
            LOADG(p0, p1, p2, p3, 7); COMPUTE(c0, c1, c2, c3, 6);
            LOADG(c0, c1, c2, c3, 0); COMPUTE(p0, p1, p2, p3, 7);
            // ^ next-iter G0 in flight across the 8 cached groups + reduce

            // 5 register-cached groups (pure VALU)
            COMPUTE(q0a, q0b, q0c, q0d,  8);
            COMPUTE(q1a, q1b, q1c, q1d,  9);
            COMPUTE(q2a, q2b, q2c, q2d, 10);
            COMPUTE(q3a, q3b, q3c, q3d, 11);

            // 3 LDS-cached groups (rows 384..479)
            {
                const int base = mb * 128 + s;
                p0 = A_lds[base]; p1 = A_lds[base + 32];
                p2 = A_lds[base + 64]; p3 = A_lds[base + 96];
                COMPUTE(p0, p1, p2, p3, 12);
            }
            {
                const int base = (mb + 32) * 128 + s;
                p0 = A_lds[base]; p1 = A_lds[base + 32];
                p2 = A_lds[base + 64]; p3 = A_lds[base + 96];
                COMPUTE(p0, p1, p2, p3, 13);
            }
            {
                const int base = (mb + 64) * 128 + s;
                p0 = A_lds[base]; p1 = A_lds[base + 32];
                p2 = A_lds[base + 64]; p3 = A_lds[base + 96];
                COMPUTE(p0, p1, p2, p3, 14);
            }

            // last register group
            COMPUTE(q4a, q4b, q4c, q4d, 15);

            // merge half-wave partials in-register (xor32) -> 16 partials
            MRG(g0.x); MRG(g0.y); MRG(g0.z); MRG(g0.w);
            MRG(g1.x); MRG(g1.y); MRG(g1.z); MRG(g1.w);
            MRG(g2.x); MRG(g2.y); MRG(g2.z); MRG(g2.w);
            MRG(g3.x); MRG(g3.y); MRG(g3.z); MRG(g3.w);
            MRG(sviol);

            if (h == 0) {
                const int gb = w * N + s * 4;
                *(float4*)(&g_lds[gb      ]) = g0;
                *(float4*)(&g_lds[gb + 128]) = g1;
                *(float4*)(&g_lds[gb + 256]) = g2;
                *(float4*)(&g_lds[gb + 384]) = g3;
                if (s == 0) sv_lds[w] = sviol;
            }
            __syncthreads();                       // barrier 1
            if (tid == 0) {
                float sacc = 0.f;
                #pragma unroll
                for (int i = 0; i < NWAVES; ++i) sacc += sv_lds[i];
                bc_active = (sacc >= DELTA) ? 1 : 0;
            }
            if (tid < N) {
                float sacc = 0.f;
                #pragma unroll
                for (int i = 0; i < NWAVES; ++i) sacc += g_lds[i * N + tid];
                gred[tid] = sacc;
            }
            __syncthreads();                       // barrier 2
            if (!bc_active) break;

            float4 q0 = *(const float4*)(&gred[  0 + s * 4]);
            float4 q1 = *(const float4*)(&gred[128 + s * 4]);
            float4 q2 = *(const float4*)(&gred[256 + s * 4]);
            float4 q3 = *(const float4*)(&gred[384 + s * 4]);
            xf0.x = fmaxf(xf0.x - (ALPHA / (1.f + SCALE*q0.x)) * q0.x, 0.f);
            xf0.y = fmaxf(xf0.y - (ALPHA / (1.f + SCALE*q0.y)) * q0.y, 0.f);
            xf0.z = fmaxf(xf0.z - (ALPHA / (1.f + SCALE*q0.z)) * q0.z, 0.f);
            xf0.w = fmaxf(xf0.w - (ALPHA / (1.f + SCALE*q0.w)) * q0.w, 0.f);
            xf1.x = fmaxf(xf1.x - (ALPHA / (1.f + SCALE*q1.x)) * q1.x, 0.f);
            xf1.y = fmaxf(xf1.y - (ALPHA / (1.f + SCALE*q1.y)) * q1.y, 0.f);
            xf1.z = fmaxf(xf1.z - (ALPHA / (1.f + SCALE*q1.z)) * q1.z, 0.f);
            xf1.w = fmaxf(xf1.w - (ALPHA / (1.f + SCALE*q1.w)) * q1.w, 0.f);
            xf2.x = fmaxf(xf2.x - (ALPHA / (1.f + SCALE*q2.x)) * q2.x, 0.f);
            xf2.y = fmaxf(xf2.y - (ALPHA / (1.f + SCALE*q2.y)) * q2.y, 0.f);
            xf2.z = fmaxf(xf2.z - (ALPHA / (1.f + SCALE*q2.z)) * q2.z, 0.f);
            xf2.w = fmaxf(xf2.w - (ALPHA / (1.f + SCALE*q2.w)) * q2.w, 0.f);
            xf3.x = fmaxf(xf3.x - (ALPHA / (1.f + SCALE*q3.x)) * q3.x, 0.f);
            xf3.y = fmaxf(xf3.y - (ALPHA / (1.f + SCALE*q3.y)) * q3.y, 0.f);
            xf3.z = fmaxf(xf3.z - (ALPHA / (1.f + SCALE*q3.z)) * q3.z, 0.f);
            xf3.w = fmaxf(xf3.w - (ALPHA / (1.f + SCALE*q3.w)) * q3.w, 0.f);
            // no 3rd barrier: gred (read above) and g_lds (written next iter,
            // pre-barrier-1) are disjoint buffers; barrier 1/2 order them.
        }
        #undef LOADG
        #undef COMPUTE
        #undef MRG
    }

    if (w == 0 && h == 0) {   // x replicated across waves/halves
        float* orow = x_out + (size_t)r * N + s * 4;
        *(float4*)(orow +   0) = xf0;
        *(float4*)(orow + 128) = xf1;
        *(float4*)(orow + 256) = xf2;
        *(float4*)(orow + 384) = xf3;
    }
}

// ---------------------------------------------------------------------------
// Fallback (round-3 proven kernel, fp32) if ws_size < 128 MiB.
// ---------------------------------------------------------------------------
__global__ __launch_bounds__(NTHREADS, 4)
void lva_kernel(const float* __restrict__ x_in,
                const float* __restrict__ A,
                const float* __restrict__ bvec,
                float* __restrict__ x_out)
{
    __shared__ float b_lds[M];
    __shared__ float g_lds[NWAVES * N];
    __shared__ float sv_lds[NWAVES];
    __shared__ int bc_active;

    const int tid  = threadIdx.x;
    const int lane = tid & 63;
    const int w    = tid >> 6;
    const int r    = blockIdx.x;

    if (tid < M) b_lds[tid] = bvec[(size_t)r * M + tid];

    const int n0 = lane * 4;
    const int n1 = 256 + lane * 4;

    const float* xrow = x_in + (size_t)r * N;
    float4 xa = *(const float4*)(xrow + n0);
    float4 xb = *(const float4*)(xrow + n1);

    const float* Ablk = A + (size_t)r * M * N + (size_t)w * N;

    __syncthreads();

    for (int t = 0; t < MAXIT; ++t) {
        float4 ga = make_float4(0.f, 0.f, 0.f, 0.f);
        float4 gb = make_float4(0.f, 0.f, 0.f, 0.f);
        float sviol = 0.f;

        #pragma unroll 1
        for (int kk = 0; kk < MPW; kk += 4) {
            const float* p0 = Ablk + (size_t)(kk + 0) * (16 * N);
            const float* p1 = Ablk + (size_t)(kk + 1) * (16 * N);
            const float* p2 = Ablk + (size_t)(kk + 2) * (16 * N);
            const float* p3 = Ablk + (size_t)(kk + 3) * (16 * N);
            float4 a0 = *(const float4*)(p0 + n0), c0 = *(const float4*)(p0 + n1);
            float4 a1 = *(const float4*)(p1 + n0), c1 = *(const float4*)(p1 + n1);
            float4 a2 = *(const float4*)(p2 + n0), c2 = *(const float4*)(p2 + n1);
            float4 a3 = *(const float4*)(p3 + n0), c3 = *(const float4*)(p3 + n1);
            float bb0 = b_lds[w + 16 * (kk + 0)];
            float bb1 = b_lds[w + 16 * (kk + 1)];
            float bb2 = b_lds[w + 16 * (kk + 2)];
            float bb3 = b_lds[w + 16 * (kk + 3)];
            float d0 = wave_sum_u(dot8(a0, c0, xa, xb));
            float d1 = wave_sum_u(dot8(a1, c1, xa, xb));
            float d2 = wave_sum_u(dot8(a2, c2, xa, xb));
            float d3 = wave_sum_u(dot8(a3, c3, xa, xb));
            float v0 = fmaxf(d0 - bb0, 0.f);
            float v1 = fmaxf(d1 - bb1, 0.f);
            float v2 = fmaxf(d2 - bb2, 0.f);
            float v3 = fmaxf(d3 - bb3, 0.f);
            sviol += v0 + v1 + v2 + v3;
            ga.x += v0*a0.x + v1*a1.x + v2*a2.x + v3*a3.x;
            ga.y += v0*a0.y + v1*a1.y + v2*a2.y + v3*a3.y;
            ga.z += v0*a0.z + v1*a1.z + v2*a2.z + v3*a3.z;
            ga.w += v0*a0.w + v1*a1.w + v2*a2.w + v3*a3.w;
            gb.x += v0*c0.x + v1*c1.x + v2*c2.x + v3*c3.x;
            gb.y += v0*c0.y + v1*c1.y + v2*c2.y + v3*c3.y;
            gb.z += v0*c0.z + v1*c1.z + v2*c2.z + v3*c3.z;
            gb.w += v0*c0.w + v1*c1.w + v2*c2.w + v3*c3.w;
        }

        if (lane == 0) sv_lds[w] = sviol;
        *(float4*)(&g_lds[w * N + n0]) = ga;
        *(float4*)(&g_lds[w * N + n1]) = gb;
        __syncthreads();
        if (tid == 0) {
            float sacc = 0.f;
            #pragma unroll
            for (int i = 0; i < NWAVES; ++i) sacc += sv_lds[i];
            bc_active = (sacc >= DELTA) ? 1 : 0;
        }
        if (tid < N) {
            float sacc = 0.f;
            #pragma unroll
            for (int i = 0; i < NWAVES; ++i) sacc += g_lds[i * N + tid];
            g_lds[tid] = sacc;
        }
        __syncthreads();
        if (!bc_active) break;

        float4 gfa = *(const float4*)(&g_lds[n0]);
        float4 gfb = *(const float4*)(&g_lds[n1]);
        xa.x = fmaxf(xa.x - (ALPHA / (1.f + SCALE*gfa.x)) * gfa.x, 0.f);
        xa.y = fmaxf(xa.y - (ALPHA / (1.f + SCALE*gfa.y)) * gfa.y, 0.f);
        xa.z = fmaxf(xa.z - (ALPHA / (1.f + SCALE*gfa.z)) * gfa.z, 0.f);
        xa.w = fmaxf(xa.w - (ALPHA / (1.f + SCALE*gfa.w)) * gfa.w, 0.f);
        xb.x = fmaxf(xb.x - (ALPHA / (1.f + SCALE*gfb.x)) * gfb.x, 0.f);
        xb.y = fmaxf(xb.y - (ALPHA / (1.f + SCALE*gfb.y)) * gfb.y, 0.f);
        xb.z = fmaxf(xb.z - (ALPHA / (1.f + SCALE*gfb.z)) * gfb.z, 0.f);
        xb.w = fmaxf(xb.w - (ALPHA / (1.f + SCALE*gfb.w)) * gfb.w, 0.f);
        __syncthreads();
    }

    float* orow = x_out + (size_t)r * N;
    if (w == 0) {
        *(float4*)(orow + n0) = xa;
        *(float4*)(orow + n1) = xb;
    }
}

extern "C" void kernel_launch(void* const* d_in, const int* in_sizes, int n_in,
                              void* d_out, int out_size, void* d_ws, size_t ws_size,
                              hipStream_t stream)
{
    const float* x  = (const float*)d_in[0];
    const float* A  = (const float*)d_in[1];
    const float* b  = (const float*)d_in[2];
    float* out      = (float*)d_out;

    if (ws_size >= WS_NEEDED) {
        lva_bf16_kernel<<<dim3(NROWS), dim3(NTHREADS), 0, stream>>>(
            x, A, b, out, (unsigned short*)d_ws);
    } else {
        lva_kernel<<<dim3(NROWS), dim3(NTHREADS), 0, stream>>>(x, A, b, out);
    }
}

// Round 4
// 3512.323 us; speedup vs baseline: 1.0482x; 1.0482x over previous
//
#include <hip/hip_runtime.h>

#define ALPHA 0.005f
#define SCALE 0.001f
#define DELTA 0.1f
#define MAXIT 51   // MAX_ITER + 1 scan steps

constexpr int N = 512;
constexpr int M = 512;
constexpr int NTHREADS = 1024;
constexpr int NWAVES = NTHREADS / 64;  // 16
constexpr int MPW = M / NWAVES;        // 32 constraint rows per wave at t=0
constexpr int NROWS = 256;             // B*S
constexpr size_t WS_NEEDED = (size_t)NROWS * M * N * 2;  // bf16 A copy workspace

// Group map (group G = rows 32G..32G+31; row m = w + 16*kk, kk = 2G + h):
//   G 0..8   -> ws (global stream, 9 groups = 288 KiB/iter/CU, ws = 72 MiB)
//   G 9..12  -> register cache slots q0..q3 (32 VGPR/lane)
//   G 13..15 -> LDS cache (96 KiB, rows 416..511)
constexpr int CACHE_M0 = 416;

template<int CTRL>
__device__ __forceinline__ float dpp_mov(float v) {
    return __int_as_float(__builtin_amdgcn_update_dpp(
        0, __float_as_int(v), CTRL, 0xF, 0xF, true));
}

// 64-lane sum (t=0 fp32 phase): 6 DPP + readlane
__device__ __forceinline__ float wave_sum_u(float d) {
    d += dpp_mov<0x111>(d);   // row_shr:1
    d += dpp_mov<0x112>(d);   // row_shr:2
    d += dpp_mov<0x114>(d);   // row_shr:4
    d += dpp_mov<0x118>(d);   // row_shr:8
    d += dpp_mov<0x142>(d);   // row_bcast:15
    d += dpp_mov<0x143>(d);   // row_bcast:31
    return __int_as_float(__builtin_amdgcn_readlane(__float_as_int(d), 63));
}

__device__ __forceinline__ float dot8(const float4& a, const float4& c,
                                      const float4& xa, const float4& xb) {
    return a.x*xa.x + a.y*xa.y + a.z*xa.z + a.w*xa.w
         + c.x*xb.x + c.y*xb.y + c.z*xb.z + c.w*xb.w;
}

// bf16 pack (RNE) / unpack
__device__ __forceinline__ unsigned pack2_bf16(float f0, float f1) {
    unsigned a = __float_as_uint(f0); a += 0x7fffu + ((a >> 16) & 1u);
    unsigned b = __float_as_uint(f1); b += 0x7fffu + ((b >> 16) & 1u);
    return (a >> 16) | (b & 0xffff0000u);
}
__device__ __forceinline__ float bflo(unsigned u) { return __uint_as_float(u << 16); }
__device__ __forceinline__ float bfhi(unsigned u) { return __uint_as_float(u & 0xffff0000u); }

__device__ __forceinline__ void unpack4(uint2 u, float4& f) {
    f.x = bflo(u.x); f.y = bfhi(u.x); f.z = bflo(u.y); f.w = bfhi(u.y);
}

// ---------------------------------------------------------------------------
// One block per (b,s) row. t=0: fp32 pass; A converted to bf16, split three
// ways: ws (G0..8), registers (G9..12, captured via pack + ds_bpermute xor32
// exchange — validated r3), LDS (G13..15). t>=1: stream 9 groups from ws
// (72 MiB, L3-friendly), rest from registers/LDS. 2 barriers/iter.
// __launch_bounds__(1024, 1): LDS caps us at 1 block/CU (4 waves/SIMD)
// regardless; (1024,4) imposed a 64-VGPR cap that spilled the reg cache (r3).
// ---------------------------------------------------------------------------
__global__ __launch_bounds__(NTHREADS, 1)
void lva_bf16_kernel(const float* __restrict__ x_in,
                     const float* __restrict__ A,
                     const float* __restrict__ bvec,
                     float* __restrict__ x_out,
                     unsigned short* __restrict__ wsA)
{
    __shared__ __align__(16) float b_lds[M];
    __shared__ __align__(16) float g_lds[NWAVES * N];      // 32 KiB: 16 partials
    __shared__ __align__(16) float gred[N];                // 2 KiB: reduced g
    __shared__ float sv_lds[NWAVES];
    __shared__ int bc_active;
    __shared__ __align__(16) uint2 A_lds[96 * 128];        // 96 KiB: rows 416..511

    const int tid  = threadIdx.x;
    const int lane = tid & 63;
    const int w    = tid >> 6;
    const int r    = blockIdx.x;
    const int h    = lane >> 5;          // half-wave index 0/1
    const int s    = lane & 31;          // lane-in-half
    const int xadr = (lane ^ 32) << 2;   // bpermute byte addr (xor32)

    if (tid < M) b_lds[tid] = bvec[(size_t)r * M + tid];

    const int n0 = lane * 4;
    const int n1 = 256 + lane * 4;

    const float* xrow = x_in + (size_t)r * N;
    float4 xa = *(const float4*)(xrow + n0);
    float4 xb = *(const float4*)(xrow + n1);

    const float* Ablk = A + (size_t)r * M * N + (size_t)w * N;
    unsigned short* Wblk = wsA + (size_t)r * M * N + (size_t)w * N;

    __syncthreads();

    bool alive = true;

    // register cache slots: q0..q3 = groups 9..12
    uint2 q0a = make_uint2(0,0), q0b = q0a, q0c = q0a, q0d = q0a;
    uint2 q1a = q0a, q1b = q0a, q1c = q0a, q1d = q0a;
    uint2 q2a = q0a, q2b = q0a, q2c = q0a, q2d = q0a;
    uint2 q3a = q0a, q3b = q0a, q3c = q0a, q3d = q0a;

    // ---- t = 0: fp32 compute; A split to ws / registers / LDS ----
    {
        float4 ga = make_float4(0.f, 0.f, 0.f, 0.f);
        float4 gb = make_float4(0.f, 0.f, 0.f, 0.f);
        float sviol = 0.f;
        float4 a0, a1, a2, a3, c0, c1, c2, c3;

        #define LOADA4(KK) do {                                               \
            const float* P0 = Ablk + (size_t)((KK) + 0) * (16 * N);           \
            const float* P1 = Ablk + (size_t)((KK) + 1) * (16 * N);           \
            const float* P2 = Ablk + (size_t)((KK) + 2) * (16 * N);           \
            const float* P3 = Ablk + (size_t)((KK) + 3) * (16 * N);           \
            a0 = *(const float4*)(P0 + n0); c0 = *(const float4*)(P0 + n1);   \
            a1 = *(const float4*)(P1 + n0); c1 = *(const float4*)(P1 + n1);   \
            a2 = *(const float4*)(P2 + n0); c2 = *(const float4*)(P2 + n1);   \
            a3 = *(const float4*)(P3 + n0); c3 = *(const float4*)(P3 + n1);   \
        } while (0)

        #define DOTGRAD4(KK) do {                                             \
            float bb0 = b_lds[w + 16 * ((KK) + 0)];                           \
            float bb1 = b_lds[w + 16 * ((KK) + 1)];                           \
            float bb2 = b_lds[w + 16 * ((KK) + 2)];                           \
            float bb3 = b_lds[w + 16 * ((KK) + 3)];                           \
            float d0 = wave_sum_u(dot8(a0, c0, xa, xb));                      \
            float d1 = wave_sum_u(dot8(a1, c1, xa, xb));                      \
            float d2 = wave_sum_u(dot8(a2, c2, xa, xb));                      \
            float d3 = wave_sum_u(dot8(a3, c3, xa, xb));                      \
            float v0 = fmaxf(d0 - bb0, 0.f);                                  \
            float v1 = fmaxf(d1 - bb1, 0.f);                                  \
            float v2 = fmaxf(d2 - bb2, 0.f);                                  \
            float v3 = fmaxf(d3 - bb3, 0.f);                                  \
            sviol += v0 + v1 + v2 + v3;                                       \
            ga.x += v0*a0.x + v1*a1.x + v2*a2.x + v3*a3.x;                    \
            ga.y += v0*a0.y + v1*a1.y + v2*a2.y + v3*a3.y;                    \
            ga.z += v0*a0.z + v1*a1.z + v2*a2.z + v3*a3.z;                    \
            ga.w += v0*a0.w + v1*a1.w + v2*a2.w + v3*a3.w;                    \
            gb.x += v0*c0.x + v1*c1.x + v2*c2.x + v3*c3.x;                    \
            gb.y += v0*c0.y + v1*c1.y + v2*c2.y + v3*c3.y;                    \
            gb.z += v0*c0.z + v1*c1.z + v2*c2.z + v3*c3.z;                    \
            gb.w += v0*c0.w + v1*c1.w + v2*c2.w + v3*c3.w;                    \
        } while (0)

        #define WS1(J, AJ, CJ) do {                                           \
            unsigned short* q = Wblk + (size_t)(J) * (16 * N);                \
            *(uint2*)(q + n0) = make_uint2(pack2_bf16(AJ.x, AJ.y),            \
                                           pack2_bf16(AJ.z, AJ.w));           \
            *(uint2*)(q + n1) = make_uint2(pack2_bf16(CJ.x, CJ.y),            \
                                           pack2_bf16(CJ.z, CJ.w));           \
        } while (0)

        #define LDS1(J, AJ, CJ) do {                                          \
            const int rl = w + 16 * (J) - CACHE_M0;                           \
            A_lds[rl * 128 + lane]      = make_uint2(pack2_bf16(AJ.x, AJ.y),  \
                                                     pack2_bf16(AJ.z, AJ.w)); \
            A_lds[rl * 128 + 64 + lane] = make_uint2(pack2_bf16(CJ.x, CJ.y),  \
                                                     pack2_bf16(CJ.z, CJ.w)); \
        } while (0)

        #define BPERM(v) (unsigned)__builtin_amdgcn_ds_bpermute(xadr, (int)(v))

        // capture row into cache slot; even kk -> owner half h=0
        #define CAPE(Q, AJ, CJ) do {                                          \
            unsigned lo0 = pack2_bf16(AJ.x, AJ.y), lo1 = pack2_bf16(AJ.z, AJ.w); \
            unsigned hi0 = pack2_bf16(CJ.x, CJ.y), hi1 = pack2_bf16(CJ.z, CJ.w); \
            unsigned rl0 = BPERM(lo0), rl1 = BPERM(lo1);                      \
            unsigned rh0 = BPERM(hi0), rh1 = BPERM(hi1);                      \
            if (h == 0) {                                                     \
                Q##a = make_uint2(lo0, lo1); Q##b = make_uint2(rl0, rl1);     \
                Q##c = make_uint2(hi0, hi1); Q##d = make_uint2(rh0, rh1);     \
            }                                                                 \
        } while (0)
        // odd kk -> owner half h=1
        #define CAPO(Q, AJ, CJ) do {                                          \
            unsigned lo0 = pack2_bf16(AJ.x, AJ.y), lo1 = pack2_bf16(AJ.z, AJ.w); \
            unsigned hi0 = pack2_bf16(CJ.x, CJ.y), hi1 = pack2_bf16(CJ.z, CJ.w); \
            unsigned rl0 = BPERM(lo0), rl1 = BPERM(lo1);                      \
            unsigned rh0 = BPERM(hi0), rh1 = BPERM(hi1);                      \
            if (h == 1) {                                                     \
                Q##a = make_uint2(rl0, rl1); Q##b = make_uint2(lo0, lo1);     \
                Q##c = make_uint2(rh0, rh1); Q##d = make_uint2(hi0, hi1);     \
            }                                                                 \
        } while (0)

        // Section A: kk 0..15 -> ws groups 0..7 (rolled)
        #pragma unroll 1
        for (int kk = 0; kk < 16; kk += 4) {
            LOADA4(kk);
            WS1(kk + 0, a0, c0); WS1(kk + 1, a1, c1);
            WS1(kk + 2, a2, c2); WS1(kk + 3, a3, c3);
            DOTGRAD4(kk);
        }
        // Section B: kk 16,17 -> ws (G8); kk 18,19 -> reg slot q0 (G9)
        LOADA4(16);
        WS1(16, a0, c0); WS1(17, a1, c1);
        CAPE(q0, a2, c2); CAPO(q0, a3, c3);
        DOTGRAD4(16);
        // Section C: kk 20..23 -> reg slots q1 (G10), q2 (G11)
        LOADA4(20);
        CAPE(q1, a0, c0); CAPO(q1, a1, c1);
        CAPE(q2, a2, c2); CAPO(q2, a3, c3);
        DOTGRAD4(20);
        // Section D: kk 24,25 -> reg slot q3 (G12); kk 26,27 -> LDS (G13)
        LOADA4(24);
        CAPE(q3, a0, c0); CAPO(q3, a1, c1);
        LDS1(26, a2, c2); LDS1(27, a3, c3);
        DOTGRAD4(24);
        // Section E: kk 28..31 -> LDS (G14, G15)
        LOADA4(28);
        LDS1(28, a0, c0); LDS1(29, a1, c1);
        LDS1(30, a2, c2); LDS1(31, a3, c3);
        DOTGRAD4(28);

        #undef LOADA4
        #undef WS1
        #undef LDS1
        #undef CAPE
        #undef CAPO
        #undef BPERM
        #undef DOTGRAD4

        if (lane == 0) sv_lds[w] = sviol;
        *(float4*)(&g_lds[w * N + n0]) = ga;
        *(float4*)(&g_lds[w * N + n1]) = gb;
        __syncthreads();
        if (tid == 0) {
            float sacc = 0.f;
            #pragma unroll
            for (int i = 0; i < NWAVES; ++i) sacc += sv_lds[i];
            bc_active = (sacc >= DELTA) ? 1 : 0;
        }
        if (tid < N) {
            float sacc = 0.f;
            #pragma unroll
            for (int i = 0; i < NWAVES; ++i) sacc += g_lds[i * N + tid];
            gred[tid] = sacc;
        }
        __syncthreads();
        if (!bc_active) {
            alive = false;
        } else {
            float4 gfa = *(const float4*)(&gred[n0]);
            float4 gfb = *(const float4*)(&gred[n1]);
            xa.x = fmaxf(xa.x - (ALPHA / (1.f + SCALE*gfa.x)) * gfa.x, 0.f);
            xa.y = fmaxf(xa.y - (ALPHA / (1.f + SCALE*gfa.y)) * gfa.y, 0.f);
            xa.z = fmaxf(xa.z - (ALPHA / (1.f + SCALE*gfa.z)) * gfa.z, 0.f);
            xa.w = fmaxf(xa.w - (ALPHA / (1.f + SCALE*gfa.w)) * gfa.w, 0.f);
            xb.x = fmaxf(xb.x - (ALPHA / (1.f + SCALE*gfb.x)) * gfb.x, 0.f);
            xb.y = fmaxf(xb.y - (ALPHA / (1.f + SCALE*gfb.y)) * gfb.y, 0.f);
            xb.z = fmaxf(xb.z - (ALPHA / (1.f + SCALE*gfb.z)) * gfb.z, 0.f);
            xb.w = fmaxf(xb.w - (ALPHA / (1.f + SCALE*gfb.w)) * gfb.w, 0.f);
        }
    }

    // ---- relayout x into 32-lane-group fragments (s*4 contiguous) ----
    __syncthreads();
    if (w == 0) {
        *(float4*)(&g_lds[n0]) = xa;
        *(float4*)(&g_lds[n1]) = xb;
    }
    __syncthreads();
    float4 xf0 = *(const float4*)(&g_lds[  0 + s * 4]);
    float4 xf1 = *(const float4*)(&g_lds[128 + s * 4]);
    float4 xf2 = *(const float4*)(&g_lds[256 + s * 4]);
    float4 xf3 = *(const float4*)(&g_lds[384 + s * 4]);
    __syncthreads();

    // ---- t = 1..50: bf16 phase, half-wave per row ----
    if (alive) {
        const uint2* Wp = (const uint2*)(wsA + (size_t)r * M * N)
                          + (w + 16 * h) * 128 + s;
        const int mb = w + 16 * h;    // b_lds base; row m = mb + 32*G

        uint2 c0, c1, c2, c3, p0, p1, p2, p3;

        #define LOADG(b0, b1, b2, b3, Gn) do {  \
            b0 = Wp[(Gn) * 4096];               \
            b1 = Wp[(Gn) * 4096 + 32];          \
            b2 = Wp[(Gn) * 4096 + 64];          \
            b3 = Wp[(Gn) * 4096 + 96];          \
        } while (0)

        #define COMPUTE(b0, b1, b2, b3, G) do {                               \
            float4 f0, f1, f2, f3;                                            \
            unpack4(b0, f0); unpack4(b1, f1);                                 \
            unpack4(b2, f2); unpack4(b3, f3);                                 \
            float d = f0.x*xf0.x + f0.y*xf0.y + f0.z*xf0.z + f0.w*xf0.w       \
                    + f1.x*xf1.x + f1.y*xf1.y + f1.z*xf1.z + f1.w*xf1.w       \
                    + f2.x*xf2.x + f2.y*xf2.y + f2.z*xf2.z + f2.w*xf2.w       \
                    + f3.x*xf3.x + f3.y*xf3.y + f3.z*xf3.z + f3.w*xf3.w;      \
            d += dpp_mov<0xB1>(d);   /* quad_perm [1,0,3,2] : xor1 */         \
            d += dpp_mov<0x4E>(d);   /* quad_perm [2,3,0,1] : xor2 */         \
            d += dpp_mov<0x141>(d);  /* row_half_mirror     : xor4 */         \
            d += dpp_mov<0x140>(d);  /* row_mirror          : xor8 */         \
            d += __int_as_float(__builtin_amdgcn_ds_swizzle(                  \
                     __float_as_int(d), 0x401F)); /* xor16 within 32 */       \
            float v = fmaxf(d - b_lds[mb + 32 * (G)], 0.f);                   \
            sviol += v;                                                       \
            g0.x += v*f0.x; g0.y += v*f0.y; g0.z += v*f0.z; g0.w += v*f0.w;   \
            g1.x += v*f1.x; g1.y += v*f1.y; g1.z += v*f1.z; g1.w += v*f1.w;   \
            g2.x += v*f2.x; g2.y += v*f2.y; g2.z += v*f2.z; g2.w += v*f2.w;   \
            g3.x += v*f3.x; g3.y += v*f3.y; g3.z += v*f3.z; g3.w += v*f3.w;   \
        } while (0)

        #define MRG(x) (x) += __int_as_float(                                 \
            __builtin_amdgcn_ds_bpermute(xadr, __float_as_int(x)))

        LOADG(c0, c1, c2, c3, 0);   // prologue: G=0 in flight

        #pragma unroll 1
        for (int t = 1; t < MAXIT; ++t) {
            float4 g0 = make_float4(0.f, 0.f, 0.f, 0.f);
            float4 g1 = make_float4(0.f, 0.f, 0.f, 0.f);
            float4 g2 = make_float4(0.f, 0.f, 0.f, 0.f);
            float4 g3 = make_float4(0.f, 0.f, 0.f, 0.f);
            float sviol = 0.f;

            // 9 global groups, paired double-buffer
            LOADG(p0, p1, p2, p3, 1); COMPUTE(c0, c1, c2, c3, 0);
            LOADG(c0, c1, c2, c3, 2); COMPUTE(p0, p1, p2, p3, 1);
            LOADG(p0, p1, p2, p3, 3); COMPUTE(c0, c1, c2, c3, 2);
            LOADG(c0, c1, c2, c3, 4); COMPUTE(p0, p1, p2, p3, 3);
            LOADG(p0, p1, p2, p3, 5); COMPUTE(c0, c1, c2, c3, 4);
            LOADG(c0, c1, c2, c3, 6); COMPUTE(p0, p1, p2, p3, 5);
            LOADG(p0, p1, p2, p3, 7); COMPUTE(c0, c1, c2, c3, 6);
            LOADG(c0, c1, c2, c3, 8); COMPUTE(p0, p1, p2, p3, 7);
            COMPUTE(c0, c1, c2, c3, 8);
            LOADG(c0, c1, c2, c3, 0);
            // ^ next-iter G0 in flight across 7 cached groups + reduce

            // 4 register-cached groups (pure VALU)
            COMPUTE(q0a, q0b, q0c, q0d,  9);
            COMPUTE(q1a, q1b, q1c, q1d, 10);
            COMPUTE(q2a, q2b, q2c, q2d, 11);
            COMPUTE(q3a, q3b, q3c, q3d, 12);

            // 3 LDS-cached groups (rows 416..511)
            {
                const int base = mb * 128 + s;
                p0 = A_lds[base]; p1 = A_lds[base + 32];
                p2 = A_lds[base + 64]; p3 = A_lds[base + 96];
                COMPUTE(p0, p1, p2, p3, 13);
            }
            {
                const int base = (mb + 32) * 128 + s;
                p0 = A_lds[base]; p1 = A_lds[base + 32];
                p2 = A_lds[base + 64]; p3 = A_lds[base + 96];
                COMPUTE(p0, p1, p2, p3, 14);
            }
            {
                const int base = (mb + 64) * 128 + s;
                p0 = A_lds[base]; p1 = A_lds[base + 32];
                p2 = A_lds[base + 64]; p3 = A_lds[base + 96];
                COMPUTE(p0, p1, p2, p3, 15);
            }

            // merge half-wave partials in-register (xor32) -> 16 partials
            MRG(g0.x); MRG(g0.y); MRG(g0.z); MRG(g0.w);
            MRG(g1.x); MRG(g1.y); MRG(g1.z); MRG(g1.w);
            MRG(g2.x); MRG(g2.y); MRG(g2.z); MRG(g2.w);
            MRG(g3.x); MRG(g3.y); MRG(g3.z); MRG(g3.w);
            MRG(sviol);

            if (h == 0) {
                const int gb = w * N + s * 4;
                *(float4*)(&g_lds[gb      ]) = g0;
                *(float4*)(&g_lds[gb + 128]) = g1;
                *(float4*)(&g_lds[gb + 256]) = g2;
                *(float4*)(&g_lds[gb + 384]) = g3;
                if (s == 0) sv_lds[w] = sviol;
            }
            __syncthreads();                       // barrier 1
            if (tid == 0) {
                float sacc = 0.f;
                #pragma unroll
                for (int i = 0; i < NWAVES; ++i) sacc += sv_lds[i];
                bc_active = (sacc >= DELTA) ? 1 : 0;
            }
            if (tid < N) {
                float sacc = 0.f;
                #pragma unroll
                for (int i = 0; i < NWAVES; ++i) sacc += g_lds[i * N + tid];
                gred[tid] = sacc;
            }
            __syncthreads();                       // barrier 2
            if (!bc_active) break;

            float4 q0 = *(const float4*)(&gred[  0 + s * 4]);
            float4 q1 = *(const float4*)(&gred[128 + s * 4]);
            float4 q2 = *(const float4*)(&gred[256 + s * 4]);
            float4 q3 = *(const float4*)(&gred[384 + s * 4]);
            xf0.x = fmaxf(xf0.x - (ALPHA / (1.f + SCALE*q0.x)) * q0.x, 0.f);
            xf0.y = fmaxf(xf0.y - (ALPHA / (1.f + SCALE*q0.y)) * q0.y, 0.f);
            xf0.z = fmaxf(xf0.z - (ALPHA / (1.f + SCALE*q0.z)) * q0.z, 0.f);
            xf0.w = fmaxf(xf0.w - (ALPHA / (1.f + SCALE*q0.w)) * q0.w, 0.f);
            xf1.x = fmaxf(xf1.x - (ALPHA / (1.f + SCALE*q1.x)) * q1.x, 0.f);
            xf1.y = fmaxf(xf1.y - (ALPHA / (1.f + SCALE*q1.y)) * q1.y, 0.f);
            xf1.z = fmaxf(xf1.z - (ALPHA / (1.f + SCALE*q1.z)) * q1.z, 0.f);
            xf1.w = fmaxf(xf1.w - (ALPHA / (1.f + SCALE*q1.w)) * q1.w, 0.f);
            xf2.x = fmaxf(xf2.x - (ALPHA / (1.f + SCALE*q2.x)) * q2.x, 0.f);
            xf2.y = fmaxf(xf2.y - (ALPHA / (1.f + SCALE*q2.y)) * q2.y, 0.f);
            xf2.z = fmaxf(xf2.z - (ALPHA / (1.f + SCALE*q2.z)) * q2.z, 0.f);
            xf2.w = fmaxf(xf2.w - (ALPHA / (1.f + SCALE*q2.w)) * q2.w, 0.f);
            xf3.x = fmaxf(xf3.x - (ALPHA / (1.f + SCALE*q3.x)) * q3.x, 0.f);
            xf3.y = fmaxf(xf3.y - (ALPHA / (1.f + SCALE*q3.y)) * q3.y, 0.f);
            xf3.z = fmaxf(xf3.z - (ALPHA / (1.f + SCALE*q3.z)) * q3.z, 0.f);
            xf3.w = fmaxf(xf3.w - (ALPHA / (1.f + SCALE*q3.w)) * q3.w, 0.f);
            // no 3rd barrier: gred (read here) and g_lds (written next iter,
            // pre-barrier-1) are disjoint buffers; barriers 1/2 order them.
        }
        #undef LOADG
        #undef COMPUTE
        #undef MRG
    }

    if (w == 0 && h == 0) {   // x replicated across waves/halves
        float* orow = x_out + (size_t)r * N + s * 4;
        *(float4*)(orow +   0) = xf0;
        *(float4*)(orow + 128) = xf1;
        *(float4*)(orow + 256) = xf2;
        *(float4*)(orow + 384) = xf3;
    }
}

// ---------------------------------------------------------------------------
// Fallback (proven fp32 kernel) if ws_size < 128 MiB.
// ---------------------------------------------------------------------------
__global__ __launch_bounds__(NTHREADS, 4)
void lva_kernel(const float* __restrict__ x_in,
                const float* __restrict__ A,
                const float* __restrict__ bvec,
                float* __restrict__ x_out)
{
    __shared__ float b_lds[M];
    __shared__ float g_lds[NWAVES * N];
    __shared__ float sv_lds[NWAVES];
    __shared__ int bc_active;

    const int tid  = threadIdx.x;
    const int lane = tid & 63;
    const int w    = tid >> 6;
    const int r    = blockIdx.x;

    if (tid < M) b_lds[tid] = bvec[(size_t)r * M + tid];

    const int n0 = lane * 4;
    const int n1 = 256 + lane * 4;

    const float* xrow = x_in + (size_t)r * N;
    float4 xa = *(const float4*)(xrow + n0);
    float4 xb = *(const float4*)(xrow + n1);

    const float* Ablk = A + (size_t)r * M * N + (size_t)w * N;

    __syncthreads();

    for (int t = 0; t < MAXIT; ++t) {
        float4 ga = make_float4(0.f, 0.f, 0.f, 0.f);
        float4 gb = make_float4(0.f, 0.f, 0.f, 0.f);
        float sviol = 0.f;

        #pragma unroll 1
        for (int kk = 0; kk < MPW; kk += 4) {
            const float* p0 = Ablk + (size_t)(kk + 0) * (16 * N);
            const float* p1 = Ablk + (size_t)(kk + 1) * (16 * N);
            const float* p2 = Ablk + (size_t)(kk + 2) * (16 * N);
            const float* p3 = Ablk + (size_t)(kk + 3) * (16 * N);
            float4 a0 = *(const float4*)(p0 + n0), c0 = *(const float4*)(p0 + n1);
            float4 a1 = *(const float4*)(p1 + n0), c1 = *(const float4*)(p1 + n1);
            float4 a2 = *(const float4*)(p2 + n0), c2 = *(const float4*)(p2 + n1);
            float4 a3 = *(const float4*)(p3 + n0), c3 = *(const float4*)(p3 + n1);
            float bb0 = b_lds[w + 16 * (kk + 0)];
            float bb1 = b_lds[w + 16 * (kk + 1)];
            float bb2 = b_lds[w + 16 * (kk + 2)];
            float bb3 = b_lds[w + 16 * (kk + 3)];
            float d0 = wave_sum_u(dot8(a0, c0, xa, xb));
            float d1 = wave_sum_u(dot8(a1, c1, xa, xb));
            float d2 = wave_sum_u(dot8(a2, c2, xa, xb));
            float d3 = wave_sum_u(dot8(a3, c3, xa, xb));
            float v0 = fmaxf(d0 - bb0, 0.f);
            float v1 = fmaxf(d1 - bb1, 0.f);
            float v2 = fmaxf(d2 - bb2, 0.f);
            float v3 = fmaxf(d3 - bb3, 0.f);
            sviol += v0 + v1 + v2 + v3;
            ga.x += v0*a0.x + v1*a1.x + v2*a2.x + v3*a3.x;
            ga.y += v0*a0.y + v1*a1.y + v2*a2.y + v3*a3.y;
            ga.z += v0*a0.z + v1*a1.z + v2*a2.z + v3*a3.z;
            ga.w += v0*a0.w + v1*a1.w + v2*a2.w + v3*a3.w;
            gb.x += v0*c0.x + v1*c1.x + v2*c2.x + v3*c3.x;
            gb.y += v0*c0.y + v1*c1.y + v2*c2.y + v3*c3.y;
            gb.z += v0*c0.z + v1*c1.z + v2*c2.z + v3*c3.z;
            gb.w += v0*c0.w + v1*c1.w + v2*c2.w + v3*c3.w;
        }

        if (lane == 0) sv_lds[w] = sviol;
        *(float4*)(&g_lds[w * N + n0]) = ga;
        *(float4*)(&g_lds[w * N + n1]) = gb;
        __syncthreads();
        if (tid == 0) {
            float sacc = 0.f;
            #pragma unroll
            for (int i = 0; i < NWAVES; ++i) sacc += sv_lds[i];
            bc_active = (sacc >= DELTA) ? 1 : 0;
        }
        if (tid < N) {
            float sacc = 0.f;
            #pragma unroll
            for (int i = 0; i < NWAVES; ++i) sacc += g_lds[i * N + tid];
            g_lds[tid] = sacc;
        }
        __syncthreads();
        if (!bc_active) break;

        float4 gfa = *(const float4*)(&g_lds[n0]);
        float4 gfb = *(const float4*)(&g_lds[n1]);
        xa.x = fmaxf(xa.x - (ALPHA / (1.f + SCALE*gfa.x)) * gfa.x, 0.f);
        xa.y = fmaxf(xa.y - (ALPHA / (1.f + SCALE*gfa.y)) * gfa.y, 0.f);
        xa.z = fmaxf(xa.z - (ALPHA / (1.f + SCALE*gfa.z)) * gfa.z, 0.f);
        xa.w = fmaxf(xa.w - (ALPHA / (1.f + SCALE*gfa.w)) * gfa.w, 0.f);
        xb.x = fmaxf(xb.x - (ALPHA / (1.f + SCALE*gfb.x)) * gfb.x, 0.f);
        xb.y = fmaxf(xb.y - (ALPHA / (1.f + SCALE*gfb.y)) * gfb.y, 0.f);
        xb.z = fmaxf(xb.z - (ALPHA / (1.f + SCALE*gfb.z)) * gfb.z, 0.f);
        xb.w = fmaxf(xb.w - (ALPHA / (1.f + SCALE*gfb.w)) * gfb.w, 0.f);
        __syncthreads();
    }

    float* orow = x_out + (size_t)r * N;
    if (w == 0) {
        *(float4*)(orow + n0) = xa;
        *(float4*)(orow + n1) = xb;
    }
}

extern "C" void kernel_launch(void* const* d_in, const int* in_sizes, int n_in,
                              void* d_out, int out_size, void* d_ws, size_t ws_size,
                              hipStream_t stream)
{
    const float* x  = (const float*)d_in[0];
    const float* A  = (const float*)d_in[1];
    const float* b  = (const float*)d_in[2];
    float* out      = (float*)d_out;

    if (ws_size >= WS_NEEDED) {
        lva_bf16_kernel<<<dim3(NROWS), dim3(NTHREADS), 0, stream>>>(
            x, A, b, out, (unsigned short*)d_ws);
    } else {
        lva_kernel<<<dim3(NROWS), dim3(NTHREADS), 0, stream>>>(x, A, b, out);
    }
}

// Round 5
// 1508.289 us; speedup vs baseline: 2.4410x; 2.3287x over previous
//
#include <hip/hip_runtime.h>

#define ALPHA 0.005f
#define SCALE 0.001f
#define DELTA 0.1f
#define MAXIT 51   // MAX_ITER + 1 scan steps

constexpr int N = 512;
constexpr int M = 512;
constexpr int NTHREADS = 1024;
constexpr int NWAVES = NTHREADS / 64;  // 16
constexpr int MPW = M / NWAVES;        // 32 constraint rows per wave at t=0
constexpr int NROWS = 256;             // B*S
constexpr size_t WS_NEEDED = (size_t)NROWS * M * N * 2;  // bf16 A copy workspace

// Group map (group G = rows 32G..32G+31; row m = w + 16*kk, kk = 2G + h):
//   G 0..11  -> ws (global stream, 12 groups = 384 KiB/iter/CU, ws = 96 MiB)
//   G 12..15 -> LDS cache (128 KiB, rows 384..511)
constexpr int CACHE_M0 = 384;

template<int CTRL>
__device__ __forceinline__ float dpp_mov(float v) {
    return __int_as_float(__builtin_amdgcn_update_dpp(
        0, __float_as_int(v), CTRL, 0xF, 0xF, true));
}

// 64-lane sum (t=0 fp32 phase): 6 DPP + readlane
__device__ __forceinline__ float wave_sum_u(float d) {
    d += dpp_mov<0x111>(d);   // row_shr:1
    d += dpp_mov<0x112>(d);   // row_shr:2
    d += dpp_mov<0x114>(d);   // row_shr:4
    d += dpp_mov<0x118>(d);   // row_shr:8
    d += dpp_mov<0x142>(d);   // row_bcast:15
    d += dpp_mov<0x143>(d);   // row_bcast:31
    return __int_as_float(__builtin_amdgcn_readlane(__float_as_int(d), 63));
}

__device__ __forceinline__ float dot8(const float4& a, const float4& c,
                                      const float4& xa, const float4& xb) {
    return a.x*xa.x + a.y*xa.y + a.z*xa.z + a.w*xa.w
         + c.x*xb.x + c.y*xb.y + c.z*xb.z + c.w*xb.w;
}

// bf16 pack (RNE) / unpack
__device__ __forceinline__ unsigned pack2_bf16(float f0, float f1) {
    unsigned a = __float_as_uint(f0); a += 0x7fffu + ((a >> 16) & 1u);
    unsigned b = __float_as_uint(f1); b += 0x7fffu + ((b >> 16) & 1u);
    return (a >> 16) | (b & 0xffff0000u);
}
__device__ __forceinline__ float bflo(unsigned u) { return __uint_as_float(u << 16); }
__device__ __forceinline__ float bfhi(unsigned u) { return __uint_as_float(u & 0xffff0000u); }

__device__ __forceinline__ void unpack4(uint2 u, float4& f) {
    f.x = bflo(u.x); f.y = bfhi(u.x); f.z = bflo(u.y); f.w = bfhi(u.y);
}

// ---------------------------------------------------------------------------
// One block per (b,s) row. t=0: fp32 pass; A converted to bf16: ws (G0..11),
// LDS cache (G12..15, 128 KiB). t>=1 (r2-proven structure): half-wave per
// row, 16 elems/lane (uint2), 2-deep double-buffer, 12 global + 4 LDS groups.
// Gradient reduction via ds_add_f32 atomics into a double-buffered 512-float
// accumulator (ping-pong, next iter zeroes the other buffer) — removes the
// 32 KiB partial buffer (freed for the 4th cached group), the per-element
// 16-read reduce phase, and the serial sviol loop. 2 barriers/iter.
// NOTE r1/r3/r4 lesson: hipcc pins this kernel shape at 64 VGPR — register
// footprint here is identical to r2 (no new persistent per-thread state).
// ---------------------------------------------------------------------------
__global__ __launch_bounds__(NTHREADS, 4)
void lva_bf16_kernel(const float* __restrict__ x_in,
                     const float* __restrict__ A,
                     const float* __restrict__ bvec,
                     float* __restrict__ x_out,
                     unsigned short* __restrict__ wsA)
{
    __shared__ __align__(16) float b_lds[M];
    __shared__ __align__(16) float gacc[2][N];     // 4 KiB: atomic accumulators
    __shared__ __align__(16) float xswap[N];       // 2 KiB: x relayout
    __shared__ float sv_acc[2];
    __shared__ __align__(16) uint2 A_lds[128 * 128];  // 128 KiB: rows 384..511

    const int tid  = threadIdx.x;
    const int lane = tid & 63;
    const int w    = tid >> 6;
    const int r    = blockIdx.x;
    const int h    = lane >> 5;          // half-wave index 0/1
    const int s    = lane & 31;          // lane-in-half
    const int xadr = (lane ^ 32) << 2;   // bpermute byte addr (xor32)

    if (tid < M) b_lds[tid] = bvec[(size_t)r * M + tid];
    if (tid < N) { gacc[0][tid] = 0.f; gacc[1][tid] = 0.f; }
    if (tid == 0) { sv_acc[0] = 0.f; sv_acc[1] = 0.f; }

    const int n0 = lane * 4;
    const int n1 = 256 + lane * 4;

    const float* xrow = x_in + (size_t)r * N;
    float4 xa = *(const float4*)(xrow + n0);
    float4 xb = *(const float4*)(xrow + n1);

    const float* Ablk = A + (size_t)r * M * N + (size_t)w * N;
    unsigned short* Wblk = wsA + (size_t)r * M * N + (size_t)w * N;

    __syncthreads();

    bool alive = true;

    // ---- t = 0: fp32 compute; A split to ws (G0..11) / LDS (G12..15) ----
    {
        float4 ga = make_float4(0.f, 0.f, 0.f, 0.f);
        float4 gb = make_float4(0.f, 0.f, 0.f, 0.f);
        float sviol = 0.f;
        float4 a0, a1, a2, a3, c0, c1, c2, c3;

        #define LOADA4(KK) do {                                               \
            const float* P0 = Ablk + (size_t)((KK) + 0) * (16 * N);           \
            const float* P1 = Ablk + (size_t)((KK) + 1) * (16 * N);           \
            const float* P2 = Ablk + (size_t)((KK) + 2) * (16 * N);           \
            const float* P3 = Ablk + (size_t)((KK) + 3) * (16 * N);           \
            a0 = *(const float4*)(P0 + n0); c0 = *(const float4*)(P0 + n1);   \
            a1 = *(const float4*)(P1 + n0); c1 = *(const float4*)(P1 + n1);   \
            a2 = *(const float4*)(P2 + n0); c2 = *(const float4*)(P2 + n1);   \
            a3 = *(const float4*)(P3 + n0); c3 = *(const float4*)(P3 + n1);   \
        } while (0)

        #define DOTGRAD4(KK) do {                                             \
            float bb0 = b_lds[w + 16 * ((KK) + 0)];                           \
            float bb1 = b_lds[w + 16 * ((KK) + 1)];                           \
            float bb2 = b_lds[w + 16 * ((KK) + 2)];                           \
            float bb3 = b_lds[w + 16 * ((KK) + 3)];                           \
            float d0 = wave_sum_u(dot8(a0, c0, xa, xb));                      \
            float d1 = wave_sum_u(dot8(a1, c1, xa, xb));                      \
            float d2 = wave_sum_u(dot8(a2, c2, xa, xb));                      \
            float d3 = wave_sum_u(dot8(a3, c3, xa, xb));                      \
            float v0 = fmaxf(d0 - bb0, 0.f);                                  \
            float v1 = fmaxf(d1 - bb1, 0.f);                                  \
            float v2 = fmaxf(d2 - bb2, 0.f);                                  \
            float v3 = fmaxf(d3 - bb3, 0.f);                                  \
            sviol += v0 + v1 + v2 + v3;                                       \
            ga.x += v0*a0.x + v1*a1.x + v2*a2.x + v3*a3.x;                    \
            ga.y += v0*a0.y + v1*a1.y + v2*a2.y + v3*a3.y;                    \
            ga.z += v0*a0.z + v1*a1.z + v2*a2.z + v3*a3.z;                    \
            ga.w += v0*a0.w + v1*a1.w + v2*a2.w + v3*a3.w;                    \
            gb.x += v0*c0.x + v1*c1.x + v2*c2.x + v3*c3.x;                    \
            gb.y += v0*c0.y + v1*c1.y + v2*c2.y + v3*c3.y;                    \
            gb.z += v0*c0.z + v1*c1.z + v2*c2.z + v3*c3.z;                    \
            gb.w += v0*c0.w + v1*c1.w + v2*c2.w + v3*c3.w;                    \
        } while (0)

        #define WS1(J, AJ, CJ) do {                                           \
            unsigned short* q = Wblk + (size_t)(J) * (16 * N);                \
            *(uint2*)(q + n0) = make_uint2(pack2_bf16(AJ.x, AJ.y),            \
                                           pack2_bf16(AJ.z, AJ.w));           \
            *(uint2*)(q + n1) = make_uint2(pack2_bf16(CJ.x, CJ.y),            \
                                           pack2_bf16(CJ.z, CJ.w));           \
        } while (0)

        #define LDS1(J, AJ, CJ) do {                                          \
            const int rl = w + 16 * (J) - CACHE_M0;                           \
            A_lds[rl * 128 + lane]      = make_uint2(pack2_bf16(AJ.x, AJ.y),  \
                                                     pack2_bf16(AJ.z, AJ.w)); \
            A_lds[rl * 128 + 64 + lane] = make_uint2(pack2_bf16(CJ.x, CJ.y),  \
                                                     pack2_bf16(CJ.z, CJ.w)); \
        } while (0)

        // kk 0..23 -> ws groups 0..11 (rolled)
        #pragma unroll 1
        for (int kk = 0; kk < 24; kk += 4) {
            LOADA4(kk);
            WS1(kk + 0, a0, c0); WS1(kk + 1, a1, c1);
            WS1(kk + 2, a2, c2); WS1(kk + 3, a3, c3);
            DOTGRAD4(kk);
        }
        // kk 24..31 -> A_lds groups 12..15
        LOADA4(24);
        LDS1(24, a0, c0); LDS1(25, a1, c1);
        LDS1(26, a2, c2); LDS1(27, a3, c3);
        DOTGRAD4(24);
        LOADA4(28);
        LDS1(28, a0, c0); LDS1(29, a1, c1);
        LDS1(30, a2, c2); LDS1(31, a3, c3);
        DOTGRAD4(28);

        #undef LOADA4
        #undef WS1
        #undef LDS1
        #undef DOTGRAD4

        // atomic accumulate into gacc[0] (64-lane layout: cols n0, n1)
        atomicAdd(&gacc[0][n0 + 0], ga.x); atomicAdd(&gacc[0][n0 + 1], ga.y);
        atomicAdd(&gacc[0][n0 + 2], ga.z); atomicAdd(&gacc[0][n0 + 3], ga.w);
        atomicAdd(&gacc[0][n1 + 0], gb.x); atomicAdd(&gacc[0][n1 + 1], gb.y);
        atomicAdd(&gacc[0][n1 + 2], gb.z); atomicAdd(&gacc[0][n1 + 3], gb.w);
        if (lane == 0) atomicAdd(&sv_acc[0], sviol);
        __syncthreads();

        float svt = sv_acc[0];
        if (svt < DELTA) {
            alive = false;
        } else {
            float4 gfa = *(const float4*)(&gacc[0][n0]);
            float4 gfb = *(const float4*)(&gacc[0][n1]);
            xa.x = fmaxf(xa.x - (ALPHA / (1.f + SCALE*gfa.x)) * gfa.x, 0.f);
            xa.y = fmaxf(xa.y - (ALPHA / (1.f + SCALE*gfa.y)) * gfa.y, 0.f);
            xa.z = fmaxf(xa.z - (ALPHA / (1.f + SCALE*gfa.z)) * gfa.z, 0.f);
            xa.w = fmaxf(xa.w - (ALPHA / (1.f + SCALE*gfa.w)) * gfa.w, 0.f);
            xb.x = fmaxf(xb.x - (ALPHA / (1.f + SCALE*gfb.x)) * gfb.x, 0.f);
            xb.y = fmaxf(xb.y - (ALPHA / (1.f + SCALE*gfb.y)) * gfb.y, 0.f);
            xb.z = fmaxf(xb.z - (ALPHA / (1.f + SCALE*gfb.z)) * gfb.z, 0.f);
            xb.w = fmaxf(xb.w - (ALPHA / (1.f + SCALE*gfb.w)) * gfb.w, 0.f);
        }
        // gacc[0] left dirty: iter t=1 zeroes it after its barrier 1.
    }

    // ---- relayout x into 32-lane-group fragments (s*4 contiguous) ----
    if (w == 0) {
        *(float4*)(&xswap[n0]) = xa;
        *(float4*)(&xswap[n1]) = xb;
    }
    __syncthreads();
    float4 xf0 = *(const float4*)(&xswap[  0 + s * 4]);
    float4 xf1 = *(const float4*)(&xswap[128 + s * 4]);
    float4 xf2 = *(const float4*)(&xswap[256 + s * 4]);
    float4 xf3 = *(const float4*)(&xswap[384 + s * 4]);

    // ---- t = 1..50: bf16 phase, half-wave per row ----
    if (alive) {
        const uint2* Wp = (const uint2*)(wsA + (size_t)r * M * N)
                          + (w + 16 * h) * 128 + s;
        const int mb = w + 16 * h;    // b_lds base; row m = mb + 32*G

        uint2 c0, c1, c2, c3, p0, p1, p2, p3;

        #define LOADG(b0, b1, b2, b3, Gn) do {  \
            b0 = Wp[(Gn) * 4096];               \
            b1 = Wp[(Gn) * 4096 + 32];          \
            b2 = Wp[(Gn) * 4096 + 64];          \
            b3 = Wp[(Gn) * 4096 + 96];          \
        } while (0)

        #define COMPUTE(b0, b1, b2, b3, G) do {                               \
            float4 f0, f1, f2, f3;                                            \
            unpack4(b0, f0); unpack4(b1, f1);                                 \
            unpack4(b2, f2); unpack4(b3, f3);                                 \
            float d = f0.x*xf0.x + f0.y*xf0.y + f0.z*xf0.z + f0.w*xf0.w       \
                    + f1.x*xf1.x + f1.y*xf1.y + f1.z*xf1.z + f1.w*xf1.w       \
                    + f2.x*xf2.x + f2.y*xf2.y + f2.z*xf2.z + f2.w*xf2.w       \
                    + f3.x*xf3.x + f3.y*xf3.y + f3.z*xf3.z + f3.w*xf3.w;      \
            d += dpp_mov<0xB1>(d);   /* quad_perm [1,0,3,2] : xor1 */         \
            d += dpp_mov<0x4E>(d);   /* quad_perm [2,3,0,1] : xor2 */         \
            d += dpp_mov<0x141>(d);  /* row_half_mirror     : xor4 */         \
            d += dpp_mov<0x140>(d);  /* row_mirror          : xor8 */         \
            d += __int_as_float(__builtin_amdgcn_ds_swizzle(                  \
                     __float_as_int(d), 0x401F)); /* xor16 within 32 */       \
            float v = fmaxf(d - b_lds[mb + 32 * (G)], 0.f);                   \
            sviol += v;                                                       \
            g0.x += v*f0.x; g0.y += v*f0.y; g0.z += v*f0.z; g0.w += v*f0.w;   \
            g1.x += v*f1.x; g1.y += v*f1.y; g1.z += v*f1.z; g1.w += v*f1.w;   \
            g2.x += v*f2.x; g2.y += v*f2.y; g2.z += v*f2.z; g2.w += v*f2.w;   \
            g3.x += v*f3.x; g3.y += v*f3.y; g3.z += v*f3.z; g3.w += v*f3.w;   \
        } while (0)

        #define MRG(x) (x) += __int_as_float(                                 \
            __builtin_amdgcn_ds_bpermute(xadr, __float_as_int(x)))

        LOADG(c0, c1, c2, c3, 0);   // prologue: G=0 in flight

        #pragma unroll 1
        for (int t = 1; t < MAXIT; ++t) {
            const int buf = t & 1;
            float4 g0 = make_float4(0.f, 0.f, 0.f, 0.f);
            float4 g1 = make_float4(0.f, 0.f, 0.f, 0.f);
            float4 g2 = make_float4(0.f, 0.f, 0.f, 0.f);
            float4 g3 = make_float4(0.f, 0.f, 0.f, 0.f);
            float sviol = 0.f;

            // 12 global groups, paired double-buffer
            LOADG(p0, p1, p2, p3,  1); COMPUTE(c0, c1, c2, c3,  0);
            LOADG(c0, c1, c2, c3,  2); COMPUTE(p0, p1, p2, p3,  1);
            LOADG(p0, p1, p2, p3,  3); COMPUTE(c0, c1, c2, c3,  2);
            LOADG(c0, c1, c2, c3,  4); COMPUTE(p0, p1, p2, p3,  3);
            LOADG(p0, p1, p2, p3,  5); COMPUTE(c0, c1, c2, c3,  4);
            LOADG(c0, c1, c2, c3,  6); COMPUTE(p0, p1, p2, p3,  5);
            LOADG(p0, p1, p2, p3,  7); COMPUTE(c0, c1, c2, c3,  6);
            LOADG(c0, c1, c2, c3,  8); COMPUTE(p0, p1, p2, p3,  7);
            LOADG(p0, p1, p2, p3,  9); COMPUTE(c0, c1, c2, c3,  8);
            LOADG(c0, c1, c2, c3, 10); COMPUTE(p0, p1, p2, p3,  9);
            LOADG(p0, p1, p2, p3, 11); COMPUTE(c0, c1, c2, c3, 10);
            COMPUTE(p0, p1, p2, p3, 11);
            LOADG(c0, c1, c2, c3, 0);
            // ^ next-iter G0 in flight across 4 LDS groups + atomics + bars

            // 4 LDS-cached groups (rows 384..511), reuse p-ring registers
            {
                const int base = mb * 128 + s;
                p0 = A_lds[base]; p1 = A_lds[base + 32];
                p2 = A_lds[base + 64]; p3 = A_lds[base + 96];
                COMPUTE(p0, p1, p2, p3, 12);
            }
            {
                const int base = (mb + 32) * 128 + s;
                p0 = A_lds[base]; p1 = A_lds[base + 32];
                p2 = A_lds[base + 64]; p3 = A_lds[base + 96];
                COMPUTE(p0, p1, p2, p3, 13);
            }
            {
                const int base = (mb + 64) * 128 + s;
                p0 = A_lds[base]; p1 = A_lds[base + 32];
                p2 = A_lds[base + 64]; p3 = A_lds[base + 96];
                COMPUTE(p0, p1, p2, p3, 14);
            }
            {
                const int base = (mb + 96) * 128 + s;
                p0 = A_lds[base]; p1 = A_lds[base + 32];
                p2 = A_lds[base + 64]; p3 = A_lds[base + 96];
                COMPUTE(p0, p1, p2, p3, 15);
            }

            // merge half-wave partials in-register (xor32), then atomics
            MRG(g0.x); MRG(g0.y); MRG(g0.z); MRG(g0.w);
            MRG(g1.x); MRG(g1.y); MRG(g1.z); MRG(g1.w);
            MRG(g2.x); MRG(g2.y); MRG(g2.z); MRG(g2.w);
            MRG(g3.x); MRG(g3.y); MRG(g3.z); MRG(g3.w);
            MRG(sviol);

            if (h == 0) {
                float* gb_ = gacc[buf];
                const int e = s * 4;
                atomicAdd(&gb_[e + 0],       g0.x); atomicAdd(&gb_[e + 1],       g0.y);
                atomicAdd(&gb_[e + 2],       g0.z); atomicAdd(&gb_[e + 3],       g0.w);
                atomicAdd(&gb_[e + 128],     g1.x); atomicAdd(&gb_[e + 129],     g1.y);
                atomicAdd(&gb_[e + 130],     g1.z); atomicAdd(&gb_[e + 131],     g1.w);
                atomicAdd(&gb_[e + 256],     g2.x); atomicAdd(&gb_[e + 257],     g2.y);
                atomicAdd(&gb_[e + 258],     g2.z); atomicAdd(&gb_[e + 259],     g2.w);
                atomicAdd(&gb_[e + 384],     g3.x); atomicAdd(&gb_[e + 385],     g3.y);
                atomicAdd(&gb_[e + 386],     g3.z); atomicAdd(&gb_[e + 387],     g3.w);
                if (s == 0) atomicAdd(&sv_acc[buf], sviol);
            }
            __syncthreads();                       // barrier 1

            float svt = sv_acc[buf];
            if (svt < DELTA) break;                // uniform: all threads agree

            // zero the other buffers (used by iter t+1; last read in iter t-1)
            if (tid < N) gacc[buf ^ 1][tid] = 0.f;
            if (tid == 0) sv_acc[buf ^ 1] = 0.f;

            float4 q0 = *(const float4*)(&gacc[buf][  0 + s * 4]);
            float4 q1 = *(const float4*)(&gacc[buf][128 + s * 4]);
            float4 q2 = *(const float4*)(&gacc[buf][256 + s * 4]);
            float4 q3 = *(const float4*)(&gacc[buf][384 + s * 4]);
            xf0.x = fmaxf(xf0.x - (ALPHA / (1.f + SCALE*q0.x)) * q0.x, 0.f);
            xf0.y = fmaxf(xf0.y - (ALPHA / (1.f + SCALE*q0.y)) * q0.y, 0.f);
            xf0.z = fmaxf(xf0.z - (ALPHA / (1.f + SCALE*q0.z)) * q0.z, 0.f);
            xf0.w = fmaxf(xf0.w - (ALPHA / (1.f + SCALE*q0.w)) * q0.w, 0.f);
            xf1.x = fmaxf(xf1.x - (ALPHA / (1.f + SCALE*q1.x)) * q1.x, 0.f);
            xf1.y = fmaxf(xf1.y - (ALPHA / (1.f + SCALE*q1.y)) * q1.y, 0.f);
            xf1.z = fmaxf(xf1.z - (ALPHA / (1.f + SCALE*q1.z)) * q1.z, 0.f);
            xf1.w = fmaxf(xf1.w - (ALPHA / (1.f + SCALE*q1.w)) * q1.w, 0.f);
            xf2.x = fmaxf(xf2.x - (ALPHA / (1.f + SCALE*q2.x)) * q2.x, 0.f);
            xf2.y = fmaxf(xf2.y - (ALPHA / (1.f + SCALE*q2.y)) * q2.y, 0.f);
            xf2.z = fmaxf(xf2.z - (ALPHA / (1.f + SCALE*q2.z)) * q2.z, 0.f);
            xf2.w = fmaxf(xf2.w - (ALPHA / (1.f + SCALE*q2.w)) * q2.w, 0.f);
            xf3.x = fmaxf(xf3.x - (ALPHA / (1.f + SCALE*q3.x)) * q3.x, 0.f);
            xf3.y = fmaxf(xf3.y - (ALPHA / (1.f + SCALE*q3.y)) * q3.y, 0.f);
            xf3.z = fmaxf(xf3.z - (ALPHA / (1.f + SCALE*q3.z)) * q3.z, 0.f);
            xf3.w = fmaxf(xf3.w - (ALPHA / (1.f + SCALE*q3.w)) * q3.w, 0.f);
            __syncthreads();                       // barrier 2 (zero -> next acc)
        }
        #undef LOADG
        #undef COMPUTE
        #undef MRG
    }

    if (w == 0 && h == 0) {   // x replicated across waves/halves
        float* orow = x_out + (size_t)r * N + s * 4;
        *(float4*)(orow +   0) = xf0;
        *(float4*)(orow + 128) = xf1;
        *(float4*)(orow + 256) = xf2;
        *(float4*)(orow + 384) = xf3;
    }
}

// ---------------------------------------------------------------------------
// Fallback (proven fp32 kernel) if ws_size < 128 MiB.
// ---------------------------------------------------------------------------
__global__ __launch_bounds__(NTHREADS, 4)
void lva_kernel(const float* __restrict__ x_in,
                const float* __restrict__ A,
                const float* __restrict__ bvec,
                float* __restrict__ x_out)
{
    __shared__ float b_lds[M];
    __shared__ float g_lds[NWAVES * N];
    __shared__ float sv_lds[NWAVES];
    __shared__ int bc_active;

    const int tid  = threadIdx.x;
    const int lane = tid & 63;
    const int w    = tid >> 6;
    const int r    = blockIdx.x;

    if (tid < M) b_lds[tid] = bvec[(size_t)r * M + tid];

    const int n0 = lane * 4;
    const int n1 = 256 + lane * 4;

    const float* xrow = x_in + (size_t)r * N;
    float4 xa = *(const float4*)(xrow + n0);
    float4 xb = *(const float4*)(xrow + n1);

    const float* Ablk = A + (size_t)r * M * N + (size_t)w * N;

    __syncthreads();

    for (int t = 0; t < MAXIT; ++t) {
        float4 ga = make_float4(0.f, 0.f, 0.f, 0.f);
        float4 gb = make_float4(0.f, 0.f, 0.f, 0.f);
        float sviol = 0.f;

        #pragma unroll 1
        for (int kk = 0; kk < MPW; kk += 4) {
            const float* p0 = Ablk + (size_t)(kk + 0) * (16 * N);
            const float* p1 = Ablk + (size_t)(kk + 1) * (16 * N);
            const float* p2 = Ablk + (size_t)(kk + 2) * (16 * N);
            const float* p3 = Ablk + (size_t)(kk + 3) * (16 * N);
            float4 a0 = *(const float4*)(p0 + n0), c0 = *(const float4*)(p0 + n1);
            float4 a1 = *(const float4*)(p1 + n0), c1 = *(const float4*)(p1 + n1);
            float4 a2 = *(const float4*)(p2 + n0), c2 = *(const float4*)(p2 + n1);
            float4 a3 = *(const float4*)(p3 + n0), c3 = *(const float4*)(p3 + n1);
            float bb0 = b_lds[w + 16 * (kk + 0)];
            float bb1 = b_lds[w + 16 * (kk + 1)];
            float bb2 = b_lds[w + 16 * (kk + 2)];
            float bb3 = b_lds[w + 16 * (kk + 3)];
            float d0 = wave_sum_u(dot8(a0, c0, xa, xb));
            float d1 = wave_sum_u(dot8(a1, c1, xa, xb));
            float d2 = wave_sum_u(dot8(a2, c2, xa, xb));
            float d3 = wave_sum_u(dot8(a3, c3, xa, xb));
            float v0 = fmaxf(d0 - bb0, 0.f);
            float v1 = fmaxf(d1 - bb1, 0.f);
            float v2 = fmaxf(d2 - bb2, 0.f);
            float v3 = fmaxf(d3 - bb3, 0.f);
            sviol += v0 + v1 + v2 + v3;
            ga.x += v0*a0.x + v1*a1.x + v2*a2.x + v3*a3.x;
            ga.y += v0*a0.y + v1*a1.y + v2*a2.y + v3*a3.y;
            ga.z += v0*a0.z + v1*a1.z + v2*a2.z + v3*a3.z;
            ga.w += v0*a0.w + v1*a1.w + v2*a2.w + v3*a3.w;
            gb.x += v0*c0.x + v1*c1.x + v2*c2.x + v3*c3.x;
            gb.y += v0*c0.y + v1*c1.y + v2*c2.y + v3*c3.y;
            gb.z += v0*c0.z + v1*c1.z + v2*c2.z + v3*c3.z;
            gb.w += v0*c0.w + v1*c1.w + v2*c2.w + v3*c3.w;
        }

        if (lane == 0) sv_lds[w] = sviol;
        *(float4*)(&g_lds[w * N + n0]) = ga;
        *(float4*)(&g_lds[w * N + n1]) = gb;
        __syncthreads();
        if (tid == 0) {
            float sacc = 0.f;
            #pragma unroll
            for (int i = 0; i < NWAVES; ++i) sacc += sv_lds[i];
            bc_active = (sacc >= DELTA) ? 1 : 0;
        }
        if (tid < N) {
            float sacc = 0.f;
            #pragma unroll
            for (int i = 0; i < NWAVES; ++i) sacc += g_lds[i * N + tid];
            g_lds[tid] = sacc;
        }
        __syncthreads();
        if (!bc_active) break;

        float4 gfa = *(const float4*)(&g_lds[n0]);
        float4 gfb = *(const float4*)(&g_lds[n1]);
        xa.x = fmaxf(xa.x - (ALPHA / (1.f + SCALE*gfa.x)) * gfa.x, 0.f);
        xa.y = fmaxf(xa.y - (ALPHA / (1.f + SCALE*gfa.y)) * gfa.y, 0.f);
        xa.z = fmaxf(xa.z - (ALPHA / (1.f + SCALE*gfa.z)) * gfa.z, 0.f);
        xa.w = fmaxf(xa.w - (ALPHA / (1.f + SCALE*gfa.w)) * gfa.w, 0.f);
        xb.x = fmaxf(xb.x - (ALPHA / (1.f + SCALE*gfb.x)) * gfb.x, 0.f);
        xb.y = fmaxf(xb.y - (ALPHA / (1.f + SCALE*gfb.y)) * gfb.y, 0.f);
        xb.z = fmaxf(xb.z - (ALPHA / (1.f + SCALE*gfb.z)) * gfb.z, 0.f);
        xb.w = fmaxf(xb.w - (ALPHA / (1.f + SCALE*gfb.w)) * gfb.w, 0.f);
        __syncthreads();
    }

    float* orow = x_out + (size_t)r * N;
    if (w == 0) {
        *(float4*)(orow + n0) = xa;
        *(float4*)(orow + n1) = xb;
    }
}

extern "C" void kernel_launch(void* const* d_in, const int* in_sizes, int n_in,
                              void* d_out, int out_size, void* d_ws, size_t ws_size,
                              hipStream_t stream)
{
    const float* x  = (const float*)d_in[0];
    const float* A  = (const float*)d_in[1];
    const float* b  = (const float*)d_in[2];
    float* out      = (float*)d_out;

    if (ws_size >= WS_NEEDED) {
        lva_bf16_kernel<<<dim3(NROWS), dim3(NTHREADS), 0, stream>>>(
            x, A, b, out, (unsigned short*)d_ws);
    } else {
        lva_kernel<<<dim3(NROWS), dim3(NTHREADS), 0, stream>>>(x, A, b, out);
    }
}

// Round 6
// 1118.269 us; speedup vs baseline: 3.2924x; 1.3488x over previous
//
#include <hip/hip_runtime.h>
#include <hip/hip_cooperative_groups.h>

#define ALPHA 0.005f
#define SCALE 0.001f
#define DELTA 0.1f
#define MAXIT 51   // MAX_ITER + 1 scan steps

constexpr int N = 512;
constexpr int M = 512;
constexpr int NTHREADS = 1024;
constexpr int NWAVES = NTHREADS / 64;  // 16
constexpr int MPW = M / NWAVES;        // 32 rows/wave (r2 kernel t=0)
constexpr int NROWS = 256;             // B*S
constexpr size_t WS_NEEDED = (size_t)NROWS * M * N * 2;  // bf16 A copy workspace

template<int CTRL>
__device__ __forceinline__ float dpp_mov(float v) {
    return __int_as_float(__builtin_amdgcn_update_dpp(
        0, __float_as_int(v), CTRL, 0xF, 0xF, true));
}

// 64-lane sum (t=0 fp32 phase): 6 DPP + readlane
__device__ __forceinline__ float wave_sum_u(float d) {
    d += dpp_mov<0x111>(d);   // row_shr:1
    d += dpp_mov<0x112>(d);   // row_shr:2
    d += dpp_mov<0x114>(d);   // row_shr:4
    d += dpp_mov<0x118>(d);   // row_shr:8
    d += dpp_mov<0x142>(d);   // row_bcast:15
    d += dpp_mov<0x143>(d);   // row_bcast:31
    return __int_as_float(__builtin_amdgcn_readlane(__float_as_int(d), 63));
}

__device__ __forceinline__ float dot8(const float4& a, const float4& c,
                                      const float4& xa, const float4& xb) {
    return a.x*xa.x + a.y*xa.y + a.z*xa.z + a.w*xa.w
         + c.x*xb.x + c.y*xb.y + c.z*xb.z + c.w*xb.w;
}

// bf16 pack (RNE) / unpack
__device__ __forceinline__ unsigned pack2_bf16(float f0, float f1) {
    unsigned a = __float_as_uint(f0); a += 0x7fffu + ((a >> 16) & 1u);
    unsigned b = __float_as_uint(f1); b += 0x7fffu + ((b >> 16) & 1u);
    return (a >> 16) | (b & 0xffff0000u);
}
__device__ __forceinline__ float bflo(unsigned u) { return __uint_as_float(u << 16); }
__device__ __forceinline__ float bfhi(unsigned u) { return __uint_as_float(u & 0xffff0000u); }

__device__ __forceinline__ void unpack4(uint2 u, float4& f) {
    f.x = bflo(u.x); f.y = bfhi(u.x); f.z = bflo(u.y); f.w = bfhi(u.y);
}

// ---------------------------------------------------------------------------
// SPLIT kernel: 2 blocks per (b,s) row (grid 512), each handles half of M
// (256 rows = 8 groups). LDS ~69 KiB -> 2 blocks/CU -> 32 waves/CU (2x TLP).
// Per iter: stream G0..6 from ws, G7 from LDS cache; halves exchange partial
// gradient + sviol via agent-scope atomics in a ws hole (rows 224..255) with
// a per-iter ticket (zeroed at start behind one grid.sync()).
// Launched cooperatively; falls back to the proven r2 kernel on any failure.
// ---------------------------------------------------------------------------
__global__ __launch_bounds__(NTHREADS, 8)
void lva_bf16_split(const float* __restrict__ x_in,
                    const float* __restrict__ A,
                    const float* __restrict__ bvec,
                    float* __restrict__ x_out,
                    unsigned short* __restrict__ wsA)
{
    __shared__ __align__(16) float b_lds[256];
    __shared__ __align__(16) float g_lds[NWAVES * N];   // 32 KiB: 16 partials
    __shared__ __align__(16) float gred[N];             // 2 KiB
    __shared__ __align__(16) float xswap[N];            // 2 KiB
    __shared__ float sv_lds[NWAVES];
    __shared__ float sv_tot[2];                         // [0]=own, [1]=partner
    __shared__ __align__(16) uint2 A_lds[32 * 128];     // 32 KiB: local G7

    const int tid  = threadIdx.x;
    const int lane = tid & 63;
    const int w    = tid >> 6;
    const int bid  = blockIdx.x;
    const int r    = bid >> 1;
    const int q    = bid & 1;            // M-half index
    const int h    = lane >> 5;
    const int s    = lane & 31;
    const int xadr = (lane ^ 32) << 2;   // bpermute byte addr (xor32)

    // exchange area in the ws hole (absolute rows 224..255 of row r)
    float* H  = (float*)(wsA + (size_t)r * M * N + 224 * N);
    int* TK   = (int*)(H + 4 * 513);     // 51 tickets
    float* XP[2] = { H + (0 * 2 + q) * 513, H + (1 * 2 + q) * 513 };        // mine
    float* PP[2] = { H + (0 * 2 + (q ^ 1)) * 513, H + (1 * 2 + (q ^ 1)) * 513 };

    if (tid < 52)
        __hip_atomic_store(&TK[tid], 0, __ATOMIC_RELAXED, __HIP_MEMORY_SCOPE_AGENT);
    cooperative_groups::this_grid().sync();   // tickets zeroed before any use

    if (tid < 256) b_lds[tid] = bvec[(size_t)r * M + q * 256 + tid];

    const int n0 = lane * 4;
    const int n1 = 256 + lane * 4;

    const float* xrow = x_in + (size_t)r * N;
    float4 xa = *(const float4*)(xrow + n0);
    float4 xb = *(const float4*)(xrow + n1);

    const float* Ablk = A + (size_t)r * M * N + (size_t)(q * 256 + w) * N;
    unsigned short* Wblk = wsA + (size_t)r * M * N + (size_t)(q * 256 + w) * N;

    __syncthreads();

    bool alive = true;
    float svt;

    // 4-barrier exchange epilogue: local reduce -> publish -> ticket -> merge
    #define EXCHG(T) do {                                                     \
        __syncthreads();                                   /* bar1 */         \
        if (tid < N) {                                                        \
            float sacc = 0.f;                                                 \
            _Pragma("unroll")                                                 \
            for (int i = 0; i < NWAVES; ++i) sacc += g_lds[i * N + tid];      \
            gred[tid] = sacc;                                                 \
            __hip_atomic_store(&XP[(T) & 1][tid], sacc,                       \
                               __ATOMIC_RELAXED, __HIP_MEMORY_SCOPE_AGENT);   \
        }                                                                     \
        if (tid == 0) {                                                       \
            float sv = 0.f;                                                   \
            _Pragma("unroll")                                                 \
            for (int i = 0; i < NWAVES; ++i) sv += sv_lds[i];                 \
            sv_tot[0] = sv;                                                   \
            __hip_atomic_store(&XP[(T) & 1][N], sv,                           \
                               __ATOMIC_RELAXED, __HIP_MEMORY_SCOPE_AGENT);   \
        }                                                                     \
        __syncthreads();                                   /* bar2 */         \
        if (tid == 0) {                                                       \
            __threadfence();                                                  \
            int my = __hip_atomic_fetch_add(&TK[(T)], 1,                      \
                         __ATOMIC_ACQ_REL, __HIP_MEMORY_SCOPE_AGENT);         \
            int tgt = (my | 1) + 1;                                           \
            while (__hip_atomic_load(&TK[(T)], __ATOMIC_ACQUIRE,              \
                                     __HIP_MEMORY_SCOPE_AGENT) < tgt)         \
                __builtin_amdgcn_s_sleep(1);                                  \
            __threadfence();                                                  \
        }                                                                     \
        __syncthreads();                                   /* bar3 */         \
        if (tid < N) {                                                        \
            float pv = __hip_atomic_load(&PP[(T) & 1][tid],                   \
                           __ATOMIC_RELAXED, __HIP_MEMORY_SCOPE_AGENT);       \
            gred[tid] += pv;                                                  \
        }                                                                     \
        if (tid == N) {                                                       \
            sv_tot[1] = __hip_atomic_load(&PP[(T) & 1][N],                    \
                            __ATOMIC_RELAXED, __HIP_MEMORY_SCOPE_AGENT);      \
        }                                                                     \
        __syncthreads();                                   /* bar4 */         \
        svt = sv_tot[0] + sv_tot[1];                                          \
    } while (0)

    // ---- t = 0: fp32 over local half (16 rows/wave); G0..6 -> ws, G7 -> LDS
    {
        float4 ga = make_float4(0.f, 0.f, 0.f, 0.f);
        float4 gb = make_float4(0.f, 0.f, 0.f, 0.f);
        float sviol = 0.f;
        float4 a0, a1, a2, a3, c0, c1, c2, c3;

        #define LOADA4(KK) do {                                               \
            const float* P0 = Ablk + (size_t)((KK) + 0) * (16 * N);           \
            const float* P1 = Ablk + (size_t)((KK) + 1) * (16 * N);           \
            const float* P2 = Ablk + (size_t)((KK) + 2) * (16 * N);           \
            const float* P3 = Ablk + (size_t)((KK) + 3) * (16 * N);           \
            a0 = *(const float4*)(P0 + n0); c0 = *(const float4*)(P0 + n1);   \
            a1 = *(const float4*)(P1 + n0); c1 = *(const float4*)(P1 + n1);   \
            a2 = *(const float4*)(P2 + n0); c2 = *(const float4*)(P2 + n1);   \
            a3 = *(const float4*)(P3 + n0); c3 = *(const float4*)(P3 + n1);   \
        } while (0)

        #define DOTGRAD4(KK) do {                                             \
            float bb0 = b_lds[w + 16 * ((KK) + 0)];                           \
            float bb1 = b_lds[w + 16 * ((KK) + 1)];                           \
            float bb2 = b_lds[w + 16 * ((KK) + 2)];                           \
            float bb3 = b_lds[w + 16 * ((KK) + 3)];                           \
            float d0 = wave_sum_u(dot8(a0, c0, xa, xb));                      \
            float d1 = wave_sum_u(dot8(a1, c1, xa, xb));                      \
            float d2 = wave_sum_u(dot8(a2, c2, xa, xb));                      \
            float d3 = wave_sum_u(dot8(a3, c3, xa, xb));                      \
            float v0 = fmaxf(d0 - bb0, 0.f);                                  \
            float v1 = fmaxf(d1 - bb1, 0.f);                                  \
            float v2 = fmaxf(d2 - bb2, 0.f);                                  \
            float v3 = fmaxf(d3 - bb3, 0.f);                                  \
            sviol += v0 + v1 + v2 + v3;                                       \
            ga.x += v0*a0.x + v1*a1.x + v2*a2.x + v3*a3.x;                    \
            ga.y += v0*a0.y + v1*a1.y + v2*a2.y + v3*a3.y;                    \
            ga.z += v0*a0.z + v1*a1.z + v2*a2.z + v3*a3.z;                    \
            ga.w += v0*a0.w + v1*a1.w + v2*a2.w + v3*a3.w;                    \
            gb.x += v0*c0.x + v1*c1.x + v2*c2.x + v3*c3.x;                    \
            gb.y += v0*c0.y + v1*c1.y + v2*c2.y + v3*c3.y;                    \
            gb.z += v0*c0.z + v1*c1.z + v2*c2.z + v3*c3.z;                    \
            gb.w += v0*c0.w + v1*c1.w + v2*c2.w + v3*c3.w;                    \
        } while (0)

        #define WS1(J, AJ, CJ) do {                                           \
            unsigned short* qq = Wblk + (size_t)(J) * (16 * N);               \
            *(uint2*)(qq + n0) = make_uint2(pack2_bf16(AJ.x, AJ.y),           \
                                            pack2_bf16(AJ.z, AJ.w));          \
            *(uint2*)(qq + n1) = make_uint2(pack2_bf16(CJ.x, CJ.y),           \
                                            pack2_bf16(CJ.z, CJ.w));          \
        } while (0)

        #define LDS1(J, AJ, CJ) do {                                          \
            const int rl = w + 16 * (J) - 224;                                \
            A_lds[rl * 128 + lane]      = make_uint2(pack2_bf16(AJ.x, AJ.y),  \
                                                     pack2_bf16(AJ.z, AJ.w)); \
            A_lds[rl * 128 + 64 + lane] = make_uint2(pack2_bf16(CJ.x, CJ.y),  \
                                                     pack2_bf16(CJ.z, CJ.w)); \
        } while (0)

        #pragma unroll 1
        for (int kk = 0; kk < 12; kk += 4) {
            LOADA4(kk);
            WS1(kk + 0, a0, c0); WS1(kk + 1, a1, c1);
            WS1(kk + 2, a2, c2); WS1(kk + 3, a3, c3);
            DOTGRAD4(kk);
        }
        LOADA4(12);
        WS1(12, a0, c0); WS1(13, a1, c1);
        LDS1(14, a2, c2); LDS1(15, a3, c3);
        DOTGRAD4(12);

        #undef LOADA4
        #undef WS1
        #undef LDS1
        #undef DOTGRAD4

        if (lane == 0) sv_lds[w] = sviol;
        *(float4*)(&g_lds[w * N + n0]) = ga;
        *(float4*)(&g_lds[w * N + n1]) = gb;

        EXCHG(0);

        if (svt < DELTA) {
            alive = false;
        } else {
            float4 gfa = *(const float4*)(&gred[n0]);
            float4 gfb = *(const float4*)(&gred[n1]);
            xa.x = fmaxf(xa.x - (ALPHA / (1.f + SCALE*gfa.x)) * gfa.x, 0.f);
            xa.y = fmaxf(xa.y - (ALPHA / (1.f + SCALE*gfa.y)) * gfa.y, 0.f);
            xa.z = fmaxf(xa.z - (ALPHA / (1.f + SCALE*gfa.z)) * gfa.z, 0.f);
            xa.w = fmaxf(xa.w - (ALPHA / (1.f + SCALE*gfa.w)) * gfa.w, 0.f);
            xb.x = fmaxf(xb.x - (ALPHA / (1.f + SCALE*gfb.x)) * gfb.x, 0.f);
            xb.y = fmaxf(xb.y - (ALPHA / (1.f + SCALE*gfb.y)) * gfb.y, 0.f);
            xb.z = fmaxf(xb.z - (ALPHA / (1.f + SCALE*gfb.z)) * gfb.z, 0.f);
            xb.w = fmaxf(xb.w - (ALPHA / (1.f + SCALE*gfb.w)) * gfb.w, 0.f);
        }
    }

    // ---- relayout x into 32-lane-group fragments (s*4 contiguous) ----
    if (w == 0) {
        *(float4*)(&xswap[n0]) = xa;
        *(float4*)(&xswap[n1]) = xb;
    }
    __syncthreads();
    float4 xf0 = *(const float4*)(&xswap[  0 + s * 4]);
    float4 xf1 = *(const float4*)(&xswap[128 + s * 4]);
    float4 xf2 = *(const float4*)(&xswap[256 + s * 4]);
    float4 xf3 = *(const float4*)(&xswap[384 + s * 4]);

    // ---- t = 1..50: bf16 phase over local half (7 ws groups + 1 LDS) ----
    if (alive) {
        const int mb = w + 16 * h;    // local row in [0,32); m_loc = mb + 32G
        const uint2* Wp = (const uint2*)(wsA + (size_t)r * M * N)
                          + (q * 256 + mb) * 128 + s;

        uint2 c0, c1, c2, c3, p0, p1, p2, p3;

        #define LOADG(b0, b1, b2, b3, Gn) do {  \
            b0 = Wp[(Gn) * 4096];               \
            b1 = Wp[(Gn) * 4096 + 32];          \
            b2 = Wp[(Gn) * 4096 + 64];          \
            b3 = Wp[(Gn) * 4096 + 96];          \
        } while (0)

        #define COMPUTE(b0, b1, b2, b3, G) do {                               \
            float4 f0, f1, f2, f3;                                            \
            unpack4(b0, f0); unpack4(b1, f1);                                 \
            unpack4(b2, f2); unpack4(b3, f3);                                 \
            float d = f0.x*xf0.x + f0.y*xf0.y + f0.z*xf0.z + f0.w*xf0.w       \
                    + f1.x*xf1.x + f1.y*xf1.y + f1.z*xf1.z + f1.w*xf1.w       \
                    + f2.x*xf2.x + f2.y*xf2.y + f2.z*xf2.z + f2.w*xf2.w       \
                    + f3.x*xf3.x + f3.y*xf3.y + f3.z*xf3.z + f3.w*xf3.w;      \
            d += dpp_mov<0xB1>(d);   /* xor1 */                               \
            d += dpp_mov<0x4E>(d);   /* xor2 */                               \
            d += dpp_mov<0x141>(d);  /* xor4 */                               \
            d += dpp_mov<0x140>(d);  /* xor8 */                               \
            d += __int_as_float(__builtin_amdgcn_ds_swizzle(                  \
                     __float_as_int(d), 0x401F)); /* xor16 within 32 */       \
            float v = fmaxf(d - b_lds[mb + 32 * (G)], 0.f);                   \
            sviol += v;                                                       \
            g0.x += v*f0.x; g0.y += v*f0.y; g0.z += v*f0.z; g0.w += v*f0.w;   \
            g1.x += v*f1.x; g1.y += v*f1.y; g1.z += v*f1.z; g1.w += v*f1.w;   \
            g2.x += v*f2.x; g2.y += v*f2.y; g2.z += v*f2.z; g2.w += v*f2.w;   \
            g3.x += v*f3.x; g3.y += v*f3.y; g3.z += v*f3.z; g3.w += v*f3.w;   \
        } while (0)

        #define MRG(x) (x) += __int_as_float(                                 \
            __builtin_amdgcn_ds_bpermute(xadr, __float_as_int(x)))

        LOADG(c0, c1, c2, c3, 0);   // prologue

        #pragma unroll 1
        for (int t = 1; t < MAXIT; ++t) {
            float4 g0 = make_float4(0.f, 0.f, 0.f, 0.f);
            float4 g1 = make_float4(0.f, 0.f, 0.f, 0.f);
            float4 g2 = make_float4(0.f, 0.f, 0.f, 0.f);
            float4 g3 = make_float4(0.f, 0.f, 0.f, 0.f);
            float sviol = 0.f;

            LOADG(p0, p1, p2, p3, 1); COMPUTE(c0, c1, c2, c3, 0);
            LOADG(c0, c1, c2, c3, 2); COMPUTE(p0, p1, p2, p3, 1);
            LOADG(p0, p1, p2, p3, 3); COMPUTE(c0, c1, c2, c3, 2);
            LOADG(c0, c1, c2, c3, 4); COMPUTE(p0, p1, p2, p3, 3);
            LOADG(p0, p1, p2, p3, 5); COMPUTE(c0, c1, c2, c3, 4);
            LOADG(c0, c1, c2, c3, 6); COMPUTE(p0, p1, p2, p3, 5);
            COMPUTE(c0, c1, c2, c3, 6);
            LOADG(c0, c1, c2, c3, 0);   // next-iter G0, in flight over epilogue

            {   // LDS-cached group 7 (local rows 224..255)
                const int base = mb * 128 + s;
                p0 = A_lds[base]; p1 = A_lds[base + 32];
                p2 = A_lds[base + 64]; p3 = A_lds[base + 96];
                COMPUTE(p0, p1, p2, p3, 7);
            }

            MRG(g0.x); MRG(g0.y); MRG(g0.z); MRG(g0.w);
            MRG(g1.x); MRG(g1.y); MRG(g1.z); MRG(g1.w);
            MRG(g2.x); MRG(g2.y); MRG(g2.z); MRG(g2.w);
            MRG(g3.x); MRG(g3.y); MRG(g3.z); MRG(g3.w);
            MRG(sviol);

            if (h == 0) {
                const int gb_ = w * N + s * 4;
                *(float4*)(&g_lds[gb_      ]) = g0;
                *(float4*)(&g_lds[gb_ + 128]) = g1;
                *(float4*)(&g_lds[gb_ + 256]) = g2;
                *(float4*)(&g_lds[gb_ + 384]) = g3;
                if (s == 0) sv_lds[w] = sviol;
            }

            EXCHG(t);

            if (svt < DELTA) break;

            float4 q0 = *(const float4*)(&gred[  0 + s * 4]);
            float4 q1 = *(const float4*)(&gred[128 + s * 4]);
            float4 q2 = *(const float4*)(&gred[256 + s * 4]);
            float4 q3 = *(const float4*)(&gred[384 + s * 4]);
            xf0.x = fmaxf(xf0.x - (ALPHA / (1.f + SCALE*q0.x)) * q0.x, 0.f);
            xf0.y = fmaxf(xf0.y - (ALPHA / (1.f + SCALE*q0.y)) * q0.y, 0.f);
            xf0.z = fmaxf(xf0.z - (ALPHA / (1.f + SCALE*q0.z)) * q0.z, 0.f);
            xf0.w = fmaxf(xf0.w - (ALPHA / (1.f + SCALE*q0.w)) * q0.w, 0.f);
            xf1.x = fmaxf(xf1.x - (ALPHA / (1.f + SCALE*q1.x)) * q1.x, 0.f);
            xf1.y = fmaxf(xf1.y - (ALPHA / (1.f + SCALE*q1.y)) * q1.y, 0.f);
            xf1.z = fmaxf(xf1.z - (ALPHA / (1.f + SCALE*q1.z)) * q1.z, 0.f);
            xf1.w = fmaxf(xf1.w - (ALPHA / (1.f + SCALE*q1.w)) * q1.w, 0.f);
            xf2.x = fmaxf(xf2.x - (ALPHA / (1.f + SCALE*q2.x)) * q2.x, 0.f);
            xf2.y = fmaxf(xf2.y - (ALPHA / (1.f + SCALE*q2.y)) * q2.y, 0.f);
            xf2.z = fmaxf(xf2.z - (ALPHA / (1.f + SCALE*q2.z)) * q2.z, 0.f);
            xf2.w = fmaxf(xf2.w - (ALPHA / (1.f + SCALE*q2.w)) * q2.w, 0.f);
            xf3.x = fmaxf(xf3.x - (ALPHA / (1.f + SCALE*q3.x)) * q3.x, 0.f);
            xf3.y = fmaxf(xf3.y - (ALPHA / (1.f + SCALE*q3.y)) * q3.y, 0.f);
            xf3.z = fmaxf(xf3.z - (ALPHA / (1.f + SCALE*q3.z)) * q3.z, 0.f);
            xf3.w = fmaxf(xf3.w - (ALPHA / (1.f + SCALE*q3.w)) * q3.w, 0.f);
        }
        #undef LOADG
        #undef COMPUTE
        #undef MRG
    }
    #undef EXCHG

    if (q == 0 && w == 0 && h == 0) {   // x replicated in both halves
        float* orow = x_out + (size_t)r * N + s * 4;
        *(float4*)(orow +   0) = xf0;
        *(float4*)(orow + 128) = xf1;
        *(float4*)(orow + 256) = xf2;
        *(float4*)(orow + 384) = xf3;
    }
}

// ---------------------------------------------------------------------------
// Fallback: r2-proven single-block kernel (910 µs), used when cooperative
// launch is unavailable or occupancy < 2 blocks/CU.
// ---------------------------------------------------------------------------
constexpr int CACHE_M0 = 416;

__global__ __launch_bounds__(NTHREADS, 4)
void lva_bf16_kernel(const float* __restrict__ x_in,
                     const float* __restrict__ A,
                     const float* __restrict__ bvec,
                     float* __restrict__ x_out,
                     unsigned short* __restrict__ wsA)
{
    __shared__ __align__(16) float b_lds[M];
    __shared__ __align__(16) float g_lds[NWAVES * N];
    __shared__ float sv_lds[NWAVES];
    __shared__ int bc_active;
    __shared__ __align__(16) uint2 A_lds[96 * 128];

    const int tid  = threadIdx.x;
    const int lane = tid & 63;
    const int w    = tid >> 6;
    const int r    = blockIdx.x;

    if (tid < M) b_lds[tid] = bvec[(size_t)r * M + tid];

    const int n0 = lane * 4;
    const int n1 = 256 + lane * 4;

    const float* xrow = x_in + (size_t)r * N;
    float4 xa = *(const float4*)(xrow + n0);
    float4 xb = *(const float4*)(xrow + n1);

    const float* Ablk = A + (size_t)r * M * N + (size_t)w * N;
    unsigned short* Wblk = wsA + (size_t)r * M * N + (size_t)w * N;

    __syncthreads();

    bool alive = true;

    {
        float4 ga = make_float4(0.f, 0.f, 0.f, 0.f);
        float4 gb = make_float4(0.f, 0.f, 0.f, 0.f);
        float sviol = 0.f;

        #define STROW(j, aj, cj) do {                                               \
            if (kk + (j) >= 26) {                                                   \
                const int rl = w + 16 * (kk + (j)) - CACHE_M0;                      \
                A_lds[rl * 128 + lane]      = make_uint2(pack2_bf16(aj.x, aj.y),    \
                                                         pack2_bf16(aj.z, aj.w));   \
                A_lds[rl * 128 + 64 + lane] = make_uint2(pack2_bf16(cj.x, cj.y),    \
                                                         pack2_bf16(cj.z, cj.w));   \
            } else {                                                                \
                unsigned short* qq = Wblk + (size_t)(kk + (j)) * (16 * N);          \
                *(uint2*)(qq + n0) = make_uint2(pack2_bf16(aj.x, aj.y),             \
                                                pack2_bf16(aj.z, aj.w));            \
                *(uint2*)(qq + n1) = make_uint2(pack2_bf16(cj.x, cj.y),             \
                                                pack2_bf16(cj.z, cj.w));            \
            }                                                                       \
        } while (0)

        #pragma unroll 1
        for (int kk = 0; kk < MPW; kk += 4) {
            const float* p0 = Ablk + (size_t)(kk + 0) * (16 * N);
            const float* p1 = Ablk + (size_t)(kk + 1) * (16 * N);
            const float* p2 = Ablk + (size_t)(kk + 2) * (16 * N);
            const float* p3 = Ablk + (size_t)(kk + 3) * (16 * N);
            float4 a0 = *(const float4*)(p0 + n0), c0 = *(const float4*)(p0 + n1);
            float4 a1 = *(const float4*)(p1 + n0), c1 = *(const float4*)(p1 + n1);
            float4 a2 = *(const float4*)(p2 + n0), c2 = *(const float4*)(p2 + n1);
            float4 a3 = *(const float4*)(p3 + n0), c3 = *(const float4*)(p3 + n1);
            STROW(0, a0, c0); STROW(1, a1, c1); STROW(2, a2, c2); STROW(3, a3, c3);
            float bb0 = b_lds[w + 16 * (kk + 0)];
            float bb1 = b_lds[w + 16 * (kk + 1)];
            float bb2 = b_lds[w + 16 * (kk + 2)];
            float bb3 = b_lds[w + 16 * (kk + 3)];
            float d0 = wave_sum_u(dot8(a0, c0, xa, xb));
            float d1 = wave_sum_u(dot8(a1, c1, xa, xb));
            float d2 = wave_sum_u(dot8(a2, c2, xa, xb));
            float d3 = wave_sum_u(dot8(a3, c3, xa, xb));
            float v0 = fmaxf(d0 - bb0, 0.f);
            float v1 = fmaxf(d1 - bb1, 0.f);
            float v2 = fmaxf(d2 - bb2, 0.f);
            float v3 = fmaxf(d3 - bb3, 0.f);
            sviol += v0 + v1 + v2 + v3;
            ga.x += v0*a0.x + v1*a1.x + v2*a2.x + v3*a3.x;
            ga.y += v0*a0.y + v1*a1.y + v2*a2.y + v3*a3.y;
            ga.z += v0*a0.z + v1*a1.z + v2*a2.z + v3*a3.z;
            ga.w += v0*a0.w + v1*a1.w + v2*a2.w + v3*a3.w;
            gb.x += v0*c0.x + v1*c1.x + v2*c2.x + v3*c3.x;
            gb.y += v0*c0.y + v1*c1.y + v2*c2.y + v3*c3.y;
            gb.z += v0*c0.z + v1*c1.z + v2*c2.z + v3*c3.z;
            gb.w += v0*c0.w + v1*c1.w + v2*c2.w + v3*c3.w;
        }
        #undef STROW

        if (lane == 0) sv_lds[w] = sviol;
        *(float4*)(&g_lds[w * N + n0]) = ga;
        *(float4*)(&g_lds[w * N + n1]) = gb;
        __syncthreads();
        if (tid == 0) {
            float s_ = 0.f;
            #pragma unroll
            for (int i = 0; i < NWAVES; ++i) s_ += sv_lds[i];
            bc_active = (s_ >= DELTA) ? 1 : 0;
        }
        if (tid < N) {
            float s_ = 0.f;
            #pragma unroll
            for (int i = 0; i < NWAVES; ++i) s_ += g_lds[i * N + tid];
            g_lds[tid] = s_;
        }
        __syncthreads();
        if (!bc_active) {
            alive = false;
        } else {
            float4 gfa = *(const float4*)(&g_lds[n0]);
            float4 gfb = *(const float4*)(&g_lds[n1]);
            xa.x = fmaxf(xa.x - (ALPHA / (1.f + SCALE*gfa.x)) * gfa.x, 0.f);
            xa.y = fmaxf(xa.y - (ALPHA / (1.f + SCALE*gfa.y)) * gfa.y, 0.f);
            xa.z = fmaxf(xa.z - (ALPHA / (1.f + SCALE*gfa.z)) * gfa.z, 0.f);
            xa.w = fmaxf(xa.w - (ALPHA / (1.f + SCALE*gfa.w)) * gfa.w, 0.f);
            xb.x = fmaxf(xb.x - (ALPHA / (1.f + SCALE*gfb.x)) * gfb.x, 0.f);
            xb.y = fmaxf(xb.y - (ALPHA / (1.f + SCALE*gfb.y)) * gfb.y, 0.f);
            xb.z = fmaxf(xb.z - (ALPHA / (1.f + SCALE*gfb.z)) * gfb.z, 0.f);
            xb.w = fmaxf(xb.w - (ALPHA / (1.f + SCALE*gfb.w)) * gfb.w, 0.f);
        }
    }

    const int h = lane >> 5;
    const int s = lane & 31;
    const int xadr = (lane ^ 32) << 2;
    __syncthreads();
    if (w == 0) {
        *(float4*)(&g_lds[n0]) = xa;
        *(float4*)(&g_lds[n1]) = xb;
    }
    __syncthreads();
    float4 xf0 = *(const float4*)(&g_lds[  0 + s * 4]);
    float4 xf1 = *(const float4*)(&g_lds[128 + s * 4]);
    float4 xf2 = *(const float4*)(&g_lds[256 + s * 4]);
    float4 xf3 = *(const float4*)(&g_lds[384 + s * 4]);
    __syncthreads();

    if (alive) {
        const uint2* Wp = (const uint2*)(wsA + (size_t)r * M * N)
                          + (w + 16 * h) * 128 + s;
        const int mb = w + 16 * h;

        uint2 c0, c1, c2, c3, p0, p1, p2, p3;

        #define LOADG(b0, b1, b2, b3, Gn) do {  \
            b0 = Wp[(Gn) * 4096];               \
            b1 = Wp[(Gn) * 4096 + 32];          \
            b2 = Wp[(Gn) * 4096 + 64];          \
            b3 = Wp[(Gn) * 4096 + 96];          \
        } while (0)

        #define COMPUTE(b0, b1, b2, b3, G) do {                               \
            float4 f0, f1, f2, f3;                                            \
            unpack4(b0, f0); unpack4(b1, f1);                                 \
            unpack4(b2, f2); unpack4(b3, f3);                                 \
            float d = f0.x*xf0.x + f0.y*xf0.y + f0.z*xf0.z + f0.w*xf0.w       \
                    + f1.x*xf1.x + f1.y*xf1.y + f1.z*xf1.z + f1.w*xf1.w       \
                    + f2.x*xf2.x + f2.y*xf2.y + f2.z*xf2.z + f2.w*xf2.w       \
                    + f3.x*xf3.x + f3.y*xf3.y + f3.z*xf3.z + f3.w*xf3.w;      \
            d += dpp_mov<0xB1>(d);                                            \
            d += dpp_mov<0x4E>(d);                                            \
            d += dpp_mov<0x141>(d);                                           \
            d += dpp_mov<0x140>(d);                                           \
            d += __int_as_float(__builtin_amdgcn_ds_swizzle(                  \
                     __float_as_int(d), 0x401F));                             \
            float v = fmaxf(d - b_lds[mb + 32 * (G)], 0.f);                   \
            sviol += v;                                                       \
            g0.x += v*f0.x; g0.y += v*f0.y; g0.z += v*f0.z; g0.w += v*f0.w;   \
            g1.x += v*f1.x; g1.y += v*f1.y; g1.z += v*f1.z; g1.w += v*f1.w;   \
            g2.x += v*f2.x; g2.y += v*f2.y; g2.z += v*f2.z; g2.w += v*f2.w;   \
            g3.x += v*f3.x; g3.y += v*f3.y; g3.z += v*f3.z; g3.w += v*f3.w;   \
        } while (0)

        #define MRG(x) (x) += __int_as_float(                                 \
            __builtin_amdgcn_ds_bpermute(xadr, __float_as_int(x)))

        LOADG(c0, c1, c2, c3, 0);

        #pragma unroll 1
        for (int t = 1; t < MAXIT; ++t) {
            float4 g0 = make_float4(0.f, 0.f, 0.f, 0.f);
            float4 g1 = make_float4(0.f, 0.f, 0.f, 0.f);
            float4 g2 = make_float4(0.f, 0.f, 0.f, 0.f);
            float4 g3 = make_float4(0.f, 0.f, 0.f, 0.f);
            float sviol = 0.f;

            #pragma unroll 1
            for (int G = 0; G < 12; G += 2) {
                LOADG(p0, p1, p2, p3, G + 1);
                COMPUTE(c0, c1, c2, c3, G);
                LOADG(c0, c1, c2, c3, G + 2);
                COMPUTE(p0, p1, p2, p3, G + 1);
            }
            COMPUTE(c0, c1, c2, c3, 12);
            LOADG(c0, c1, c2, c3, 0);

            {
                const int base = mb * 128 + s;
                p0 = A_lds[base]; p1 = A_lds[base + 32];
                p2 = A_lds[base + 64]; p3 = A_lds[base + 96];
                COMPUTE(p0, p1, p2, p3, 13);
            }
            {
                const int base = (mb + 32) * 128 + s;
                p0 = A_lds[base]; p1 = A_lds[base + 32];
                p2 = A_lds[base + 64]; p3 = A_lds[base + 96];
                COMPUTE(p0, p1, p2, p3, 14);
            }
            {
                const int base = (mb + 64) * 128 + s;
                p0 = A_lds[base]; p1 = A_lds[base + 32];
                p2 = A_lds[base + 64]; p3 = A_lds[base + 96];
                COMPUTE(p0, p1, p2, p3, 15);
            }

            MRG(g0.x); MRG(g0.y); MRG(g0.z); MRG(g0.w);
            MRG(g1.x); MRG(g1.y); MRG(g1.z); MRG(g1.w);
            MRG(g2.x); MRG(g2.y); MRG(g2.z); MRG(g2.w);
            MRG(g3.x); MRG(g3.y); MRG(g3.z); MRG(g3.w);
            MRG(sviol);

            if (h == 0) {
                const int gb_ = w * N + s * 4;
                *(float4*)(&g_lds[gb_      ]) = g0;
                *(float4*)(&g_lds[gb_ + 128]) = g1;
                *(float4*)(&g_lds[gb_ + 256]) = g2;
                *(float4*)(&g_lds[gb_ + 384]) = g3;
                if (s == 0) sv_lds[w] = sviol;
            }
            __syncthreads();
            if (tid == 0) {
                float sacc = 0.f;
                #pragma unroll
                for (int i = 0; i < NWAVES; ++i) sacc += sv_lds[i];
                bc_active = (sacc >= DELTA) ? 1 : 0;
            }
            __syncthreads();
            if (tid < N) {
                float sacc = 0.f;
                #pragma unroll
                for (int i = 0; i < NWAVES; ++i) sacc += g_lds[i * N + tid];
                g_lds[NWAVES * N - N + tid] = sacc;   // stash in last row
            }
            __syncthreads();
            if (!bc_active) break;

            float4 q0 = *(const float4*)(&g_lds[NWAVES * N - N +   0 + s * 4]);
            float4 q1 = *(const float4*)(&g_lds[NWAVES * N - N + 128 + s * 4]);
            float4 q2 = *(const float4*)(&g_lds[NWAVES * N - N + 256 + s * 4]);
            float4 q3 = *(const float4*)(&g_lds[NWAVES * N - N + 384 + s * 4]);
            xf0.x = fmaxf(xf0.x - (ALPHA / (1.f + SCALE*q0.x)) * q0.x, 0.f);
            xf0.y = fmaxf(xf0.y - (ALPHA / (1.f + SCALE*q0.y)) * q0.y, 0.f);
            xf0.z = fmaxf(xf0.z - (ALPHA / (1.f + SCALE*q0.z)) * q0.z, 0.f);
            xf0.w = fmaxf(xf0.w - (ALPHA / (1.f + SCALE*q0.w)) * q0.w, 0.f);
            xf1.x = fmaxf(xf1.x - (ALPHA / (1.f + SCALE*q1.x)) * q1.x, 0.f);
            xf1.y = fmaxf(xf1.y - (ALPHA / (1.f + SCALE*q1.y)) * q1.y, 0.f);
            xf1.z = fmaxf(xf1.z - (ALPHA / (1.f + SCALE*q1.z)) * q1.z, 0.f);
            xf1.w = fmaxf(xf1.w - (ALPHA / (1.f + SCALE*q1.w)) * q1.w, 0.f);
            xf2.x = fmaxf(xf2.x - (ALPHA / (1.f + SCALE*q2.x)) * q2.x, 0.f);
            xf2.y = fmaxf(xf2.y - (ALPHA / (1.f + SCALE*q2.y)) * q2.y, 0.f);
            xf2.z = fmaxf(xf2.z - (ALPHA / (1.f + SCALE*q2.z)) * q2.z, 0.f);
            xf2.w = fmaxf(xf2.w - (ALPHA / (1.f + SCALE*q2.w)) * q2.w, 0.f);
            xf3.x = fmaxf(xf3.x - (ALPHA / (1.f + SCALE*q3.x)) * q3.x, 0.f);
            xf3.y = fmaxf(xf3.y - (ALPHA / (1.f + SCALE*q3.y)) * q3.y, 0.f);
            xf3.z = fmaxf(xf3.z - (ALPHA / (1.f + SCALE*q3.z)) * q3.z, 0.f);
            xf3.w = fmaxf(xf3.w - (ALPHA / (1.f + SCALE*q3.w)) * q3.w, 0.f);
            __syncthreads();
        }
        #undef LOADG
        #undef COMPUTE
        #undef MRG
    }

    if (w == 0 && h == 0) {
        float* orow = x_out + (size_t)r * N + s * 4;
        *(float4*)(orow +   0) = xf0;
        *(float4*)(orow + 128) = xf1;
        *(float4*)(orow + 256) = xf2;
        *(float4*)(orow + 384) = xf3;
    }
}

// ---------------------------------------------------------------------------
// Fallback (proven fp32 kernel) if ws_size < 128 MiB.
// ---------------------------------------------------------------------------
__global__ __launch_bounds__(NTHREADS, 4)
void lva_kernel(const float* __restrict__ x_in,
                const float* __restrict__ A,
                const float* __restrict__ bvec,
                float* __restrict__ x_out)
{
    __shared__ float b_lds[M];
    __shared__ float g_lds[NWAVES * N];
    __shared__ float sv_lds[NWAVES];
    __shared__ int bc_active;

    const int tid  = threadIdx.x;
    const int lane = tid & 63;
    const int w    = tid >> 6;
    const int r    = blockIdx.x;

    if (tid < M) b_lds[tid] = bvec[(size_t)r * M + tid];

    const int n0 = lane * 4;
    const int n1 = 256 + lane * 4;

    const float* xrow = x_in + (size_t)r * N;
    float4 xa = *(const float4*)(xrow + n0);
    float4 xb = *(const float4*)(xrow + n1);

    const float* Ablk = A + (size_t)r * M * N + (size_t)w * N;

    __syncthreads();

    for (int t = 0; t < MAXIT; ++t) {
        float4 ga = make_float4(0.f, 0.f, 0.f, 0.f);
        float4 gb = make_float4(0.f, 0.f, 0.f, 0.f);
        float sviol = 0.f;

        #pragma unroll 1
        for (int kk = 0; kk < MPW; kk += 4) {
            const float* p0 = Ablk + (size_t)(kk + 0) * (16 * N);
            const float* p1 = Ablk + (size_t)(kk + 1) * (16 * N);
            const float* p2 = Ablk + (size_t)(kk + 2) * (16 * N);
            const float* p3 = Ablk + (size_t)(kk + 3) * (16 * N);
            float4 a0 = *(const float4*)(p0 + n0), c0 = *(const float4*)(p0 + n1);
            float4 a1 = *(const float4*)(p1 + n0), c1 = *(const float4*)(p1 + n1);
            float4 a2 = *(const float4*)(p2 + n0), c2 = *(const float4*)(p2 + n1);
            float4 a3 = *(const float4*)(p3 + n0), c3 = *(const float4*)(p3 + n1);
            float bb0 = b_lds[w + 16 * (kk + 0)];
            float bb1 = b_lds[w + 16 * (kk + 1)];
            float bb2 = b_lds[w + 16 * (kk + 2)];
            float bb3 = b_lds[w + 16 * (kk + 3)];
            float d0 = wave_sum_u(dot8(a0, c0, xa, xb));
            float d1 = wave_sum_u(dot8(a1, c1, xa, xb));
            float d2 = wave_sum_u(dot8(a2, c2, xa, xb));
            float d3 = wave_sum_u(dot8(a3, c3, xa, xb));
            float v0 = fmaxf(d0 - bb0, 0.f);
            float v1 = fmaxf(d1 - bb1, 0.f);
            float v2 = fmaxf(d2 - bb2, 0.f);
            float v3 = fmaxf(d3 - bb3, 0.f);
            sviol += v0 + v1 + v2 + v3;
            ga.x += v0*a0.x + v1*a1.x + v2*a2.x + v3*a3.x;
            ga.y += v0*a0.y + v1*a1.y + v2*a2.y + v3*a3.y;
            ga.z += v0*a0.z + v1*a1.z + v2*a2.z + v3*a3.z;
            ga.w += v0*a0.w + v1*a1.w + v2*a2.w + v3*a3.w;
            gb.x += v0*c0.x + v1*c1.x + v2*c2.x + v3*c3.x;
            gb.y += v0*c0.y + v1*c1.y + v2*c2.y + v3*c3.y;
            gb.z += v0*c0.z + v1*c1.z + v2*c2.z + v3*c3.z;
            gb.w += v0*c0.w + v1*c1.w + v2*c2.w + v3*c3.w;
        }

        if (lane == 0) sv_lds[w] = sviol;
        *(float4*)(&g_lds[w * N + n0]) = ga;
        *(float4*)(&g_lds[w * N + n1]) = gb;
        __syncthreads();
        if (tid == 0) {
            float sacc = 0.f;
            #pragma unroll
            for (int i = 0; i < NWAVES; ++i) sacc += sv_lds[i];
            bc_active = (sacc >= DELTA) ? 1 : 0;
        }
        if (tid < N) {
            float sacc = 0.f;
            #pragma unroll
            for (int i = 0; i < NWAVES; ++i) sacc += g_lds[i * N + tid];
            g_lds[tid] = sacc;
        }
        __syncthreads();
        if (!bc_active) break;

        float4 gfa = *(const float4*)(&g_lds[n0]);
        float4 gfb = *(const float4*)(&g_lds[n1]);
        xa.x = fmaxf(xa.x - (ALPHA / (1.f + SCALE*gfa.x)) * gfa.x, 0.f);
        xa.y = fmaxf(xa.y - (ALPHA / (1.f + SCALE*gfa.y)) * gfa.y, 0.f);
        xa.z = fmaxf(xa.z - (ALPHA / (1.f + SCALE*gfa.z)) * gfa.z, 0.f);
        xa.w = fmaxf(xa.w - (ALPHA / (1.f + SCALE*gfa.w)) * gfa.w, 0.f);
        xb.x = fmaxf(xb.x - (ALPHA / (1.f + SCALE*gfb.x)) * gfb.x, 0.f);
        xb.y = fmaxf(xb.y - (ALPHA / (1.f + SCALE*gfb.y)) * gfb.y, 0.f);
        xb.z = fmaxf(xb.z - (ALPHA / (1.f + SCALE*gfb.z)) * gfb.z, 0.f);
        xb.w = fmaxf(xb.w - (ALPHA / (1.f + SCALE*gfb.w)) * gfb.w, 0.f);
        __syncthreads();
    }

    float* orow = x_out + (size_t)r * N;
    if (w == 0) {
        *(float4*)(orow + n0) = xa;
        *(float4*)(orow + n1) = xb;
    }
}

extern "C" void kernel_launch(void* const* d_in, const int* in_sizes, int n_in,
                              void* d_out, int out_size, void* d_ws, size_t ws_size,
                              hipStream_t stream)
{
    const float* x  = (const float*)d_in[0];
    const float* A  = (const float*)d_in[1];
    const float* b  = (const float*)d_in[2];
    float* out      = (float*)d_out;

    if (ws_size >= WS_NEEDED) {
        unsigned short* ws = (unsigned short*)d_ws;
        int maxb = 0;
        hipError_t oe = hipOccupancyMaxActiveBlocksPerMultiprocessor(
            &maxb, lva_bf16_split, NTHREADS, 0);
        if (oe == hipSuccess && maxb >= 2) {
            void* kargs[] = { (void*)&x, (void*)&A, (void*)&b,
                              (void*)&out, (void*)&ws };
            hipError_t e = hipLaunchCooperativeKernel(
                (void*)lva_bf16_split, dim3(2 * NROWS), dim3(NTHREADS),
                kargs, 0, stream);
            if (e == hipSuccess) return;
            (void)hipGetLastError();   // clear sticky error, fall back
        } else {
            (void)hipGetLastError();
        }
        lva_bf16_kernel<<<dim3(NROWS), dim3(NTHREADS), 0, stream>>>(
            x, A, b, out, ws);
    } else {
        lva_kernel<<<dim3(NROWS), dim3(NTHREADS), 0, stream>>>(x, A, b, out);
    }
}